// Round 12
// baseline (268.130 us; speedup 1.0000x reference)
//
// Round 12: REVERT level-2 (unexplained 0.195 absmax fail). Base = round-10
// exact (265us pass). knn split: knn_try (3^3 accept, proven path) pushes
// failures to a worklist; knn_full (round-6 full scan, proven path) processes
// only those ~10% queries at full machine width — kills the mixed-block tail.
#include <hip/hip_runtime.h>
#include <hip/hip_bf16.h>
#include <cstdint>
#include <cstddef>

#define N_NODES 10000
#define KNN_K 20
#define NEDGE (N_NODES * KNN_K)
#define NBATCH 157                 // ceil(10000/64)
#define POS4_PAD 10048             // 157*64
#define NCELL 4096                 // 16x16x16 spatial cells, h=0.5
#define NPX 1250                   // nodes per XCD chunk (10000/8)

using bf16x8 = __attribute__((ext_vector_type(8))) short;
using f32x4  = __attribute__((ext_vector_type(4))) float;

__device__ __forceinline__ float bf_lo(unsigned int u) {
  union { unsigned int i; float f; } c; c.i = u << 16; return c.f;
}
__device__ __forceinline__ float bf_hi(unsigned int u) {
  union { unsigned int i; float f; } c; c.i = u & 0xFFFF0000u; return c.f;
}
__device__ __forceinline__ unsigned short f2bf(float f) {
  union { float f; unsigned int i; } c; c.f = f;
  unsigned int u = c.i;
  u += 0x7FFFu + ((u >> 16) & 1u);   // RNE
  return (unsigned short)(u >> 16);
}

__device__ __forceinline__ void gll16(const void* g, void* l) {
  __builtin_amdgcn_global_load_lds(
      (const __attribute__((address_space(1))) unsigned int*)g,
      (__attribute__((address_space(3))) unsigned int*)l,
      16, 0, 0);
}

// ---------------- transpose f32 [srows][scols] -> bf16 dst[col][dcol0 + row] ----------------
__global__ __launch_bounds__(256) void transpose_f32_bf16(
    const float* __restrict__ src0, unsigned short* __restrict__ dst,
    int srows, int scols, int dstride, size_t slice_elems, int dcol_per_slice)
{
  __shared__ float lds[64 * 65];
  const int z = blockIdx.z;
  const float* src = src0 + (size_t)z * slice_elems;
  const int dcol0 = z * dcol_per_slice;
  const int c0 = blockIdx.x * 64;
  const int r0 = blockIdx.y * 64;
  const int tid = threadIdx.x;
#pragma unroll
  for (int q = 0; q < 4; ++q) {
    int unit = q * 256 + tid;            // 1024 float4 units
    int rr = unit >> 4;                  // 0..63
    int cu = unit & 15;                  // 0..15
    int r = r0 + rr, c = c0 + cu * 4;
    float4 v = make_float4(0.f, 0.f, 0.f, 0.f);
    if (r < srows && c + 3 < scols) v = *(const float4*)&src[(size_t)r * scols + c];
    lds[rr * 65 + cu * 4 + 0] = v.x;
    lds[rr * 65 + cu * 4 + 1] = v.y;
    lds[rr * 65 + cu * 4 + 2] = v.z;
    lds[rr * 65 + cu * 4 + 3] = v.w;
  }
  __syncthreads();
#pragma unroll
  for (int q = 0; q < 2; ++q) {
    int unit = q * 256 + tid;            // 512 units of 8 bf16
    int cl = unit >> 3;                  // src col within tile (= dst row)
    int ru = unit & 7;
    int c = c0 + cl;
    if (c < scols) {
      unsigned short tmp[8];
#pragma unroll
      for (int j = 0; j < 8; ++j) tmp[j] = f2bf(lds[(ru * 8 + j) * 65 + cl]);
      uint4 o;
      o.x = (unsigned int)tmp[0] | ((unsigned int)tmp[1] << 16);
      o.y = (unsigned int)tmp[2] | ((unsigned int)tmp[3] << 16);
      o.z = (unsigned int)tmp[4] | ((unsigned int)tmp[5] << 16);
      o.w = (unsigned int)tmp[6] | ((unsigned int)tmp[7] << 16);
      *(uint4*)&dst[(size_t)c * dstride + dcol0 + r0 + ru * 8] = o;
    }
  }
}

// ---- pos4: pack (x,y,z,|p|^2); pad w=+INF; zero counts/cursor/nfail; cell hist ----
__global__ __launch_bounds__(256) void pos4_kernel(
    const float* __restrict__ pos, float4* __restrict__ pos4,
    int* __restrict__ counts, int* __restrict__ cursor,
    int* __restrict__ cellid, int* __restrict__ cellcnt,
    int* __restrict__ nfail)
{
  int c = blockIdx.x * 256 + threadIdx.x;      // grid 40 -> 10240 threads
  if (c == 0) *nfail = 0;
  if (c < POS4_PAD) {
    float4 v;
    if (c < N_NODES) {
      float x = pos[c * 3 + 0], y = pos[c * 3 + 1], z = pos[c * 3 + 2];
      v = make_float4(x, y, z, x * x + y * y + z * z);
      int cx = min(15, max(0, (int)floorf((x + 4.0f) * 2.0f)));
      int cy = min(15, max(0, (int)floorf((y + 4.0f) * 2.0f)));
      int cz = min(15, max(0, (int)floorf((z + 4.0f) * 2.0f)));
      int cell = (cx << 8) | (cy << 4) | cz;
      cellid[c] = cell;
      atomicAdd(&cellcnt[cell], 1);
      counts[c] = 0; cursor[c] = 0;
    } else {
      v = make_float4(0.f, 0.f, 0.f, __builtin_inff());   // d -> +INF
    }
    pos4[c] = v;
  }
}

// cell-histogram exclusive scan: 1 block, 16 cells/thread
__global__ __launch_bounds__(256) void cellscan_kernel(
    const int* __restrict__ cellcnt, int* __restrict__ cellptr)
{
  __shared__ int part[256];
  const int tid = threadIdx.x;
  const int base = tid * 16;
  int cv[16];
  int s = 0;
#pragma unroll
  for (int q = 0; q < 4; ++q) {
    int4 v = *(const int4*)&cellcnt[base + q * 4];
    cv[q * 4 + 0] = v.x; cv[q * 4 + 1] = v.y;
    cv[q * 4 + 2] = v.z; cv[q * 4 + 3] = v.w;
    s += v.x + v.y + v.z + v.w;
  }
  part[tid] = s;
  __syncthreads();
  for (int off = 1; off < 256; off <<= 1) {
    int add = (tid >= off) ? part[tid - off] : 0;
    __syncthreads();
    part[tid] += add;
    __syncthreads();
  }
  int run = part[tid] - s;
#pragma unroll
  for (int q = 0; q < 16; ++q) { cellptr[base + q] = run; run += cv[q]; }
  if (tid == 255) cellptr[NCELL] = run;
}

// counting-sort scatter: perm (cell-grouped node ids) + pos4s (sorted coords)
__global__ __launch_bounds__(256) void perm_kernel(
    const int* __restrict__ cellid, const int* __restrict__ cellptr,
    int* __restrict__ cellcur, int* __restrict__ perm,
    const float4* __restrict__ pos4, float4* __restrict__ pos4s)
{
  int c = blockIdx.x * 256 + threadIdx.x;
  if (c < N_NODES) {
    int cell = cellid[c];
    int p = atomicAdd(&cellcur[cell], 1);
    int slot = cellptr[cell] + p;
    perm[slot] = c;
    pos4s[slot] = pos4[c];
  }
}

// identical expression everywhere -> bit-identical distances
__device__ __forceinline__ float knn_dist(float4 pi, float4 s) {
  float dot = fmaf(pi.x, s.x, fmaf(pi.y, s.y, pi.z * s.z));
  return fmaf(-2.0f, dot, pi.w + s.w);
}

__device__ __forceinline__ void insert8(float r[8], float k) {
  // r ascending; r_j = median(k, r_{j-1}, r_j)
  asm("v_med3_f32 %0, %1, %2, %3" : "=v"(r[7]) : "v"(k), "v"(r[6]), "v"(r[7]));
  asm("v_med3_f32 %0, %1, %2, %3" : "=v"(r[6]) : "v"(k), "v"(r[5]), "v"(r[6]));
  asm("v_med3_f32 %0, %1, %2, %3" : "=v"(r[5]) : "v"(k), "v"(r[4]), "v"(r[5]));
  asm("v_med3_f32 %0, %1, %2, %3" : "=v"(r[4]) : "v"(k), "v"(r[3]), "v"(r[4]));
  asm("v_med3_f32 %0, %1, %2, %3" : "=v"(r[3]) : "v"(k), "v"(r[2]), "v"(r[3]));
  asm("v_med3_f32 %0, %1, %2, %3" : "=v"(r[2]) : "v"(k), "v"(r[1]), "v"(r[2]));
  asm("v_med3_f32 %0, %1, %2, %3" : "=v"(r[1]) : "v"(k), "v"(r[0]), "v"(r[1]));
  r[0] = fminf(r[0], k);
}

__device__ __forceinline__ float merge_tau20(float r[8], int lane) {
  const float INF = __builtin_inff();
  float tau = INF;
#pragma unroll
  for (int t = 0; t < KNN_K; ++t) {
    float m = r[0];
    m = fminf(m, __shfl_xor(m, 1));
    m = fminf(m, __shfl_xor(m, 2));
    m = fminf(m, __shfl_xor(m, 4));
    m = fminf(m, __shfl_xor(m, 8));
    m = fminf(m, __shfl_xor(m, 16));
    m = fminf(m, __shfl_xor(m, 32));
    unsigned long long who = __ballot(r[0] == m);
    int srcl = __ffsll(who) - 1;
    if (lane == srcl) {
#pragma unroll
      for (int z = 0; z < 7; ++z) r[z] = r[z + 1];
      r[7] = INF;
    }
    tau = m;
  }
  return tau;   // exact 20th smallest (INF if <20 candidates)
}

__device__ __forceinline__ void emit_hits(
    int i, bool valid, float d, float tau, int cid, int lane, int& cnt,
    int* __restrict__ knn_out)
{
  unsigned long long less = __ballot(valid && d < tau);
  unsigned long long eq   = __ballot(valid && d == tau);
  if (less) {
    if (valid && d < tau) {
      int pos = cnt + (int)__popcll(less & ((1ull << lane) - 1ull));
      if (pos < KNN_K) knn_out[i * KNN_K + pos] = cid;
    }
    cnt += (int)__popcll(less);
  }
  if (eq && cnt < KNN_K) {
    if (valid && d == tau) {
      int pos = cnt + (int)__popcll(eq & ((1ull << lane) - 1ull));
      if (pos < KNN_K) knn_out[i * KNN_K + pos] = cid;
    }
    cnt = min(KNN_K, cnt + (int)__popcll(eq));
  }
}

// ---------------- kNN try: 3^3 grid-pruned exact (round-10 path); else worklist ----------------
__global__ __launch_bounds__(256) void knn_try_kernel(
    const float4* __restrict__ pos4, const float4* __restrict__ pos4s,
    const int* __restrict__ perm, const int* __restrict__ cellptr,
    int* __restrict__ knn_out, int* __restrict__ wl, int* __restrict__ nfail)
{
  const int lane = threadIdx.x & 63, wave = threadIdx.x >> 6;
  const int wid = blockIdx.x * 4 + wave;
  const int i = perm[wid];                         // perm-ordered queries: L2 locality
  const float4 pi = pos4[i];
  const float INF = __builtin_inff();

  const int cx = min(15, max(0, (int)floorf((pi.x + 4.0f) * 2.0f)));
  const int cy = min(15, max(0, (int)floorf((pi.y + 4.0f) * 2.0f)));
  const int cz = min(15, max(0, (int)floorf((pi.z + 4.0f) * 2.0f)));
  const int x0 = max(cx - 1, 0), x1 = min(cx + 1, 15);
  const int y0 = max(cy - 1, 0), y1 = min(cy + 1, 15);
  const int z0 = max(cz - 1, 0), z1 = min(cz + 1, 15);

  float r[8];
#pragma unroll
  for (int q = 0; q < 8; ++q) r[q] = INF;

  // phase A: top-8 over the <=27-cell block (z-contiguous ranges)
  for (int X = x0; X <= x1; ++X)
    for (int Y = y0; Y <= y1; ++Y) {
      const int cb = (X << 8) | (Y << 4);
      const int s0 = cellptr[cb + z0], s1 = cellptr[cb + z1 + 1];
      for (int c0 = s0; c0 < s1; c0 += 64) {
        const int slot = c0 + lane;
        const int idx = min(slot, s1 - 1);
        const float4 s = pos4s[idx];
        const int nid = perm[idx];
        float d = knn_dist(pi, s);
        float k = (slot < s1 && nid != i) ? d : INF;
        insert8(r, k);
      }
    }
  float tau = merge_tau20(r, lane);

  // exactness margin: distance from query to scanned-region boundary
  float mx = INF, my = INF, mz = INF;
  if (x0 > 0)  mx = pi.x - (x0 * 0.5f - 4.0f);
  if (x1 < 15) mx = fminf(mx, ((x1 + 1) * 0.5f - 4.0f) - pi.x);
  if (y0 > 0)  my = pi.y - (y0 * 0.5f - 4.0f);
  if (y1 < 15) my = fminf(my, ((y1 + 1) * 0.5f - 4.0f) - pi.y);
  if (z0 > 0)  mz = pi.z - (z0 * 0.5f - 4.0f);
  if (z1 < 15) mz = fminf(mz, ((z1 + 1) * 0.5f - 4.0f) - pi.z);
  const float marg = fminf(mx, fminf(my, mz));

  if (tau < marg * marg) {
    // accepted: ball(sqrt(tau)) inside scanned region -> exact neighbor set
    int cnt = 0;
    for (int X = x0; X <= x1; ++X)
      for (int Y = y0; Y <= y1; ++Y) {
        const int cb = (X << 8) | (Y << 4);
        const int s0 = cellptr[cb + z0], s1 = cellptr[cb + z1 + 1];
        for (int c0 = s0; c0 < s1; c0 += 64) {
          const int slot = c0 + lane;
          const int idx = min(slot, s1 - 1);
          const float4 s = pos4s[idx];
          const int nid = perm[idx];
          float d = knn_dist(pi, s);
          bool valid = (slot < s1) && (nid != i);
          emit_hits(i, valid, d, tau, nid, lane, cnt, knn_out);
        }
      }
    return;
  }

  // failed: defer to knn_full (round-6 exact full scan)
  if (lane == 0) {
    int slot = atomicAdd(nfail, 1);
    wl[slot] = i;
  }
}

// ---------------- kNN full scan for worklist queries (round-6 exact path) ----------------
__global__ __launch_bounds__(256) void knn_full_kernel(
    const float4* __restrict__ pos4, const int* __restrict__ wl,
    const int* __restrict__ nfail, int* __restrict__ knn_out)
{
  const int lane = threadIdx.x & 63, wave = threadIdx.x >> 6;
  const int w = blockIdx.x * 4 + wave;
  if (w >= *nfail) return;                         // no barriers below: safe
  const int i = wl[w];
  const float4 pi = pos4[i];
  const float INF = __builtin_inff();

  float r[8];
#pragma unroll
  for (int q = 0; q < 8; ++q) r[q] = INF;
#pragma unroll 4
  for (int b = 0; b < NBATCH; ++b) {
    const int cid = b * 64 + lane;
    const float4 s = pos4[cid];
    float d = knn_dist(pi, s);                    // pad rows: +INF
    float k = (cid == i) ? INF : d;
    insert8(r, k);
  }
  float tau = merge_tau20(r, lane);
  int cnt = 0;
  for (int b = 0; b < NBATCH; ++b) {
    const int cid = b * 64 + lane;
    const float4 s = pos4[cid];
    float d = knn_dist(pi, s);
    bool valid = (cid != i);
    emit_hits(i, valid, d, tau, cid, lane, cnt, knn_out);
  }
}

// ---------------- reverse-CSR build ----------------
__global__ __launch_bounds__(256) void count_kernel(
    const int* __restrict__ knn, int* __restrict__ counts)
{
  int e = blockIdx.x * 256 + threadIdx.x;
  if (e < NEDGE) atomicAdd(&counts[knn[e]], 1);
}

// node-degree exclusive scan (int4 loads; 250 threads x 40 exact)
__global__ __launch_bounds__(256) void scan_kernel(
    const int* __restrict__ counts, int* __restrict__ rptr)
{
  __shared__ int part[256];
  const int tid = threadIdx.x;
  const int base = tid * 40;                       // 250*40 = 10000 exact
  int s = 0;
  int cv[40];
  if (tid < 250) {
#pragma unroll
    for (int q = 0; q < 10; ++q) {
      int4 v = *(const int4*)&counts[base + q * 4];
      cv[q * 4 + 0] = v.x; cv[q * 4 + 1] = v.y;
      cv[q * 4 + 2] = v.z; cv[q * 4 + 3] = v.w;
      s += v.x + v.y + v.z + v.w;
    }
  }
  part[tid] = s;
  __syncthreads();
  for (int off = 1; off < 256; off <<= 1) {
    int add = (tid >= off) ? part[tid - off] : 0;
    __syncthreads();
    part[tid] += add;
    __syncthreads();
  }
  int run = part[tid] - s;                         // exclusive offset
  if (tid < 250) {
#pragma unroll
    for (int q = 0; q < 40; ++q) { rptr[base + q] = run; run += cv[q]; }
  }
  if (tid == 255) rptr[N_NODES] = run;
}

__global__ __launch_bounds__(256) void fill_kernel(
    const int* __restrict__ knn, const int* __restrict__ rptr,
    int* __restrict__ cursor, int* __restrict__ rsrc)
{
  int e = blockIdx.x * 256 + threadIdx.x;
  if (e < NEDGE) {
    int j = knn[e];
    int i = e / KNN_K;
    int p = atomicAdd(&cursor[j], 1);
    rsrc[rptr[j] + p] = i;
  }
}

// sort each reverse-adjacency list ascending (bitonic-64 per wave)
__global__ __launch_bounds__(256) void sort_kernel(
    const int* __restrict__ rptr, int* __restrict__ rsrc)
{
  const int lane = threadIdx.x & 63, wave = threadIdx.x >> 6;
  const int j = blockIdx.x * 4 + wave;
  const int s0 = rptr[j], s1 = rptr[j + 1], deg = s1 - s0;
  if (deg <= 64) {
    int v = (lane < deg) ? rsrc[s0 + lane] : 0x7FFFFFFF;
#pragma unroll
    for (int k = 2; k <= 64; k <<= 1) {
#pragma unroll
      for (int m = k >> 1; m > 0; m >>= 1) {
        int other = __shfl_xor(v, m);
        bool up = ((lane & k) == 0);
        bool lower = ((lane & m) == 0);
        v = (up == lower) ? min(v, other) : max(v, other);
      }
    }
    if (lane < deg) rsrc[s0 + lane] = v;
  } else if (lane == 0) {
    for (int a = s0 + 1; a < s1; ++a) {
      int v = rsrc[a];
      int b = a - 1;
      while (b >= s0 && rsrc[b] > v) { rsrc[b + 1] = rsrc[b]; --b; }
      rsrc[b + 1] = v;
    }
  }
}

// ---------------- prop: out[j] = scale2 * sum_{i in rev(j)} t[i] - prev[j] ----------------
// XCD-chunked spatial schedule (perm is cell-sorted -> L2-local gathers)
__global__ __launch_bounds__(256) void prop_kernel(
    const unsigned short* __restrict__ tin, const unsigned short* __restrict__ tprev,
    unsigned short* __restrict__ tout, const int* __restrict__ rptr,
    const int* __restrict__ rsrc, const int* __restrict__ perm, float scale2)
{
  const int wave = threadIdx.x >> 6, lane = threadIdx.x & 63;
  const int b = blockIdx.x;                        // grid 2504
  const int xcd = b & 7, qb = b >> 3;
  const int local = qb * 4 + wave;
  if (local >= NPX) return;                        // no barriers below: safe
  const int j = perm[xcd * NPX + local];
  const int s0 = rptr[j], s1 = rptr[j + 1];
  const size_t coff = (size_t)lane * 8;

  float a0[8], a1[8], a2[8], a3[8];
#pragma unroll
  for (int q = 0; q < 8; ++q) { a0[q] = 0.f; a1[q] = 0.f; a2[q] = 0.f; a3[q] = 0.f; }

  for (int base = s0; base < s1; base += 64) {
    const int clen = min(64, s1 - base);
    int myidx = (base + lane < s1) ? rsrc[base + lane] : 0;
    int t = 0;
    for (; t + 4 <= clen; t += 4) {
      int i0 = __shfl(myidx, t);
      int i1 = __shfl(myidx, t + 1);
      int i2 = __shfl(myidx, t + 2);
      int i3 = __shfl(myidx, t + 3);
      uint4 v0 = *(const uint4*)&tin[(size_t)i0 * 512 + coff];
      uint4 v1 = *(const uint4*)&tin[(size_t)i1 * 512 + coff];
      uint4 v2 = *(const uint4*)&tin[(size_t)i2 * 512 + coff];
      uint4 v3 = *(const uint4*)&tin[(size_t)i3 * 512 + coff];
      a0[0] += bf_lo(v0.x); a0[1] += bf_hi(v0.x); a0[2] += bf_lo(v0.y); a0[3] += bf_hi(v0.y);
      a0[4] += bf_lo(v0.z); a0[5] += bf_hi(v0.z); a0[6] += bf_lo(v0.w); a0[7] += bf_hi(v0.w);
      a1[0] += bf_lo(v1.x); a1[1] += bf_hi(v1.x); a1[2] += bf_lo(v1.y); a1[3] += bf_hi(v1.y);
      a1[4] += bf_lo(v1.z); a1[5] += bf_hi(v1.z); a1[6] += bf_lo(v1.w); a1[7] += bf_hi(v1.w);
      a2[0] += bf_lo(v2.x); a2[1] += bf_hi(v2.x); a2[2] += bf_lo(v2.y); a2[3] += bf_hi(v2.y);
      a2[4] += bf_lo(v2.z); a2[5] += bf_hi(v2.z); a2[6] += bf_lo(v2.w); a2[7] += bf_hi(v2.w);
      a3[0] += bf_lo(v3.x); a3[1] += bf_hi(v3.x); a3[2] += bf_lo(v3.y); a3[3] += bf_hi(v3.y);
      a3[4] += bf_lo(v3.z); a3[5] += bf_hi(v3.z); a3[6] += bf_lo(v3.w); a3[7] += bf_hi(v3.w);
    }
    for (; t < clen; ++t) {
      int i0 = __shfl(myidx, t);
      uint4 v0 = *(const uint4*)&tin[(size_t)i0 * 512 + coff];
      a0[0] += bf_lo(v0.x); a0[1] += bf_hi(v0.x); a0[2] += bf_lo(v0.y); a0[3] += bf_hi(v0.y);
      a0[4] += bf_lo(v0.z); a0[5] += bf_hi(v0.z); a0[6] += bf_lo(v0.w); a0[7] += bf_hi(v0.w);
    }
  }

  float pv[8] = {0.f, 0.f, 0.f, 0.f, 0.f, 0.f, 0.f, 0.f};
  if (tprev != nullptr) {
    uint4 p = *(const uint4*)&tprev[(size_t)j * 512 + coff];
    pv[0] = bf_lo(p.x); pv[1] = bf_hi(p.x);
    pv[2] = bf_lo(p.y); pv[3] = bf_hi(p.y);
    pv[4] = bf_lo(p.z); pv[5] = bf_hi(p.z);
    pv[6] = bf_lo(p.w); pv[7] = bf_hi(p.w);
  }
  unsigned short o16[8];
#pragma unroll
  for (int q = 0; q < 8; ++q) {
    float acc = (a0[q] + a1[q]) + (a2[q] + a3[q]);   // fixed tree, deterministic
    o16[q] = f2bf(scale2 * acc - pv[q]);
  }
  uint4 o;
  o.x = (unsigned int)o16[0] | ((unsigned int)o16[1] << 16);
  o.y = (unsigned int)o16[2] | ((unsigned int)o16[3] << 16);
  o.z = (unsigned int)o16[4] | ((unsigned int)o16[5] << 16);
  o.w = (unsigned int)o16[6] | ((unsigned int)o16[7] << 16);
  *(uint4*)&tout[(size_t)j * 512 + coff] = o;
}

// ---------------- GEMM: C[o][n] = sum_kc A[n][kc] * B[kc][o] + bias[o] ----------------
__global__ __launch_bounds__(256) void gemm_kernel(
    const unsigned short* __restrict__ A,
    const unsigned short* __restrict__ Bt,
    const float* __restrict__ bias,
    float* __restrict__ C)
{
  __shared__ __align__(16) char smem[64 * 132 * 4];   // 33792B: tiles(32KB) / epilogue(33KB)
  unsigned short* As = (unsigned short*)smem;         // [128][64] bf16
  unsigned short* Bs = As + 128 * 64;                 // [128 o][64 k] bf16
  float* eps = (float*)smem;                          // [64 o][132] f32

  const int tid = threadIdx.x;
  const int wave = tid >> 6, lane = tid & 63;
  const int l15 = lane & 15, hi = lane >> 4;
  const int wr = wave >> 1, wc = wave & 1;
  const int n0 = blockIdx.x * 128;
  const int o0 = blockIdx.y * 128;

  f32x4 acc[4][4];
#pragma unroll
  for (int a = 0; a < 4; ++a)
#pragma unroll
    for (int b = 0; b < 4; ++b) acc[a][b] = (f32x4){0.f, 0.f, 0.f, 0.f};

  for (int kt = 0; kt < 40; ++kt) {
    const int k0 = kt * 64;
    const int ko = k0 >> 9;
    const int c0 = k0 & 511;
    const unsigned short* Ab = A + (size_t)ko * ((size_t)N_NODES * 512);
#pragma unroll
    for (int q = 0; q < 4; ++q) {
      int idx = (wave * 4 + q) * 64 + lane;     // 16B unit id, 0..1023
      int r = idx >> 3, u = idx & 7;
      gll16(Ab + (size_t)(n0 + r) * 512 + c0 + u * 8, As + (size_t)(wave * 4 + q) * 512);
    }
#pragma unroll
    for (int q = 0; q < 4; ++q) {
      int idx = (wave * 4 + q) * 64 + lane;
      int r = idx >> 3, u = idx & 7;
      gll16(Bt + (size_t)(o0 + r) * 2560 + k0 + u * 8, Bs + (size_t)(wave * 4 + q) * 512);
    }
    __syncthreads();
#pragma unroll
    for (int kk = 0; kk < 2; ++kk) {
      bf16x8 af[4], bfr[4];
#pragma unroll
      for (int mi = 0; mi < 4; ++mi)
        af[mi] = *(const bf16x8*)(As + ((wr * 64 + mi * 16 + l15) * 64 + kk * 32 + hi * 8));
#pragma unroll
      for (int ni = 0; ni < 4; ++ni)
        bfr[ni] = *(const bf16x8*)(Bs + ((wc * 64 + ni * 16 + l15) * 64 + kk * 32 + hi * 8));
#pragma unroll
      for (int mi = 0; mi < 4; ++mi)
#pragma unroll
        for (int ni = 0; ni < 4; ++ni)
          acc[mi][ni] = __builtin_amdgcn_mfma_f32_16x16x32_bf16(af[mi], bfr[ni], acc[mi][ni], 0, 0, 0);
    }
    __syncthreads();
  }

  // epilogue: LDS-transposed coalesced store of C[o][n] + bias
#pragma unroll
  for (int h = 0; h < 2; ++h) {
    __syncthreads();
    if (wc == h) {
#pragma unroll
      for (int mi = 0; mi < 4; ++mi)
#pragma unroll
        for (int ni = 0; ni < 4; ++ni) {
          int o_l = ni * 16 + l15;                   // 0..63 within half
          int nb = wr * 64 + mi * 16 + hi * 4;       // 0..124, x4 aligned
          *(f32x4*)&eps[o_l * 132 + nb] = acc[mi][ni];
        }
    }
    __syncthreads();
#pragma unroll
    for (int q = 0; q < 8; ++q) {
      int unit = q * 256 + tid;                      // 2048 float4 units
      int o_l = unit >> 5, nu = unit & 31;
      int n = n0 + nu * 4;
      if (n < N_NODES) {
        int o = o0 + h * 64 + o_l;
        f32x4 v = *(const f32x4*)&eps[o_l * 132 + nu * 4];
        float bo = bias[o];
        v = v + bo;
        *(f32x4*)&C[(size_t)o * N_NODES + n] = v;
      }
    }
  }
}

extern "C" void kernel_launch(void* const* d_in, const int* in_sizes, int n_in,
                              void* d_out, int out_size, void* d_ws, size_t ws_size,
                              hipStream_t stream)
{
  const float* x        = (const float*)d_in[0];   // [512][10000]
  const float* position = (const float*)d_in[1];   // [10000][3]
  const float* theta    = (const float*)d_in[2];   // [5][512][512]
  const float* bias     = (const float*)d_in[3];   // [512]

  char* ws = (char*)d_ws;
  size_t off = 0;
  auto alloc = [&](size_t bytes) -> void* {
    void* p = ws + off;
    off = (off + bytes + 255) & ~(size_t)255;
    return p;
  };
  unsigned short* TxAll   = (unsigned short*)alloc(5ull * N_NODES * 512 * 2 + 131072); // +128-row pad
  unsigned short* thetabT = (unsigned short*)alloc(512ull * 2560 * 2);
  float4* pos4  = (float4*)alloc((size_t)POS4_PAD * 16);
  float4* pos4s = (float4*)alloc((size_t)N_NODES * 16);
  int* knn    = (int*)alloc((size_t)NEDGE * 4);
  int* rptr   = (int*)alloc((size_t)(N_NODES + 1) * 4);
  int* counts = (int*)alloc((size_t)N_NODES * 4);
  int* cursor = (int*)alloc((size_t)N_NODES * 4);
  int* rsrc   = (int*)alloc((size_t)NEDGE * 4);
  int* cellcnt = (int*)alloc((size_t)NCELL * 4);   // contiguous with cellcur:
  int* cellcur = (int*)alloc((size_t)NCELL * 4);   // one memset covers both
  int* cellptr = (int*)alloc((size_t)(NCELL + 1) * 4);
  int* cellid  = (int*)alloc((size_t)N_NODES * 4);
  int* perm    = (int*)alloc((size_t)N_NODES * 4);
  int* wl      = (int*)alloc((size_t)N_NODES * 4);
  int* nfail   = (int*)alloc(256);
  if (ws_size < off) return;   // insufficient scratch

  // theta [5][512][512] -> thetabT [o=512][kc=2560]
  transpose_f32_bf16<<<dim3(8, 8, 5), 256, 0, stream>>>(
      theta, thetabT, 512, 512, 2560, (size_t)512 * 512, 512);
  // x [512][10000] -> Tx0 [10000][512]
  transpose_f32_bf16<<<dim3(157, 8, 1), 256, 0, stream>>>(
      x, TxAll, 512, N_NODES, 512, 0, 0);

  hipMemsetAsync(cellcnt, 0, (size_t)((char*)cellptr - (char*)cellcnt), stream);
  pos4_kernel<<<40, 256, 0, stream>>>(position, pos4, counts, cursor, cellid, cellcnt, nfail);
  cellscan_kernel<<<1, 256, 0, stream>>>(cellcnt, cellptr);
  perm_kernel<<<40, 256, 0, stream>>>(cellid, cellptr, cellcur, perm, pos4, pos4s);

  knn_try_kernel<<<2500, 256, 0, stream>>>(pos4, pos4s, perm, cellptr, knn, wl, nfail);
  knn_full_kernel<<<2500, 256, 0, stream>>>(pos4, wl, nfail, knn);

  count_kernel<<<(NEDGE + 255) / 256, 256, 0, stream>>>(knn, counts);
  scan_kernel<<<1, 256, 0, stream>>>(counts, rptr);
  fill_kernel<<<(NEDGE + 255) / 256, 256, 0, stream>>>(knn, rptr, cursor, rsrc);
  sort_kernel<<<2500, 256, 0, stream>>>(rptr, rsrc);

  unsigned short* Tx0 = TxAll;
  unsigned short* Tx1 = TxAll + 1ull * N_NODES * 512;
  unsigned short* Tx2 = TxAll + 2ull * N_NODES * 512;
  unsigned short* Tx3 = TxAll + 3ull * N_NODES * 512;
  unsigned short* Tx4 = TxAll + 4ull * N_NODES * 512;

  // Tx1 = prop(Tx0) = -0.05*sum ; Tx_k = 2*prop(Tx_{k-1}) - Tx_{k-2} = -0.10*sum - prev
  prop_kernel<<<2504, 256, 0, stream>>>(Tx0, nullptr, Tx1, rptr, rsrc, perm, -0.05f);
  prop_kernel<<<2504, 256, 0, stream>>>(Tx1, Tx0,     Tx2, rptr, rsrc, perm, -0.10f);
  prop_kernel<<<2504, 256, 0, stream>>>(Tx2, Tx1,     Tx3, rptr, rsrc, perm, -0.10f);
  prop_kernel<<<2504, 256, 0, stream>>>(Tx3, Tx2,     Tx4, rptr, rsrc, perm, -0.10f);

  gemm_kernel<<<dim3(79, 4), 256, 0, stream>>>(TxAll, thetabT, bias, (float*)d_out);
}

// Round 13
// 249.052 us; speedup vs baseline: 1.0766x; 1.0766x over previous
//
// Round 13: GEMM overhaul — (1) T2 pre-swizzled-source XOR bank-conflict fix
// (9.7M conflicts = ~16us), (2) double-buffered 2-phase K-pipeline (latency was
// serially exposed at 1.2 blocks/CU), (3) XCD-chunked n-major 1-D grid.
// knn split / props / CSR identical to round-12 pass (268us, gemm 66.5us).
#include <hip/hip_runtime.h>
#include <hip/hip_bf16.h>
#include <cstdint>
#include <cstddef>

#define N_NODES 10000
#define KNN_K 20
#define NEDGE (N_NODES * KNN_K)
#define NBATCH 157                 // ceil(10000/64)
#define POS4_PAD 10048             // 157*64
#define NCELL 4096                 // 16x16x16 spatial cells, h=0.5
#define NPX 1250                   // nodes per XCD chunk (10000/8)
#define GM_PAIRS 316               // 79 n-tiles x 4 o-tiles

using bf16x8 = __attribute__((ext_vector_type(8))) short;
using f32x4  = __attribute__((ext_vector_type(4))) float;

__device__ __forceinline__ float bf_lo(unsigned int u) {
  union { unsigned int i; float f; } c; c.i = u << 16; return c.f;
}
__device__ __forceinline__ float bf_hi(unsigned int u) {
  union { unsigned int i; float f; } c; c.i = u & 0xFFFF0000u; return c.f;
}
__device__ __forceinline__ unsigned short f2bf(float f) {
  union { float f; unsigned int i; } c; c.f = f;
  unsigned int u = c.i;
  u += 0x7FFFu + ((u >> 16) & 1u);   // RNE
  return (unsigned short)(u >> 16);
}

__device__ __forceinline__ void gll16(const void* g, void* l) {
  __builtin_amdgcn_global_load_lds(
      (const __attribute__((address_space(1))) unsigned int*)g,
      (__attribute__((address_space(3))) unsigned int*)l,
      16, 0, 0);
}

// ---------------- transpose f32 [srows][scols] -> bf16 dst[col][dcol0 + row] ----------------
__global__ __launch_bounds__(256) void transpose_f32_bf16(
    const float* __restrict__ src0, unsigned short* __restrict__ dst,
    int srows, int scols, int dstride, size_t slice_elems, int dcol_per_slice)
{
  __shared__ float lds[64 * 65];
  const int z = blockIdx.z;
  const float* src = src0 + (size_t)z * slice_elems;
  const int dcol0 = z * dcol_per_slice;
  const int c0 = blockIdx.x * 64;
  const int r0 = blockIdx.y * 64;
  const int tid = threadIdx.x;
#pragma unroll
  for (int q = 0; q < 4; ++q) {
    int unit = q * 256 + tid;            // 1024 float4 units
    int rr = unit >> 4;                  // 0..63
    int cu = unit & 15;                  // 0..15
    int r = r0 + rr, c = c0 + cu * 4;
    float4 v = make_float4(0.f, 0.f, 0.f, 0.f);
    if (r < srows && c + 3 < scols) v = *(const float4*)&src[(size_t)r * scols + c];
    lds[rr * 65 + cu * 4 + 0] = v.x;
    lds[rr * 65 + cu * 4 + 1] = v.y;
    lds[rr * 65 + cu * 4 + 2] = v.z;
    lds[rr * 65 + cu * 4 + 3] = v.w;
  }
  __syncthreads();
#pragma unroll
  for (int q = 0; q < 2; ++q) {
    int unit = q * 256 + tid;            // 512 units of 8 bf16
    int cl = unit >> 3;                  // src col within tile (= dst row)
    int ru = unit & 7;
    int c = c0 + cl;
    if (c < scols) {
      unsigned short tmp[8];
#pragma unroll
      for (int j = 0; j < 8; ++j) tmp[j] = f2bf(lds[(ru * 8 + j) * 65 + cl]);
      uint4 o;
      o.x = (unsigned int)tmp[0] | ((unsigned int)tmp[1] << 16);
      o.y = (unsigned int)tmp[2] | ((unsigned int)tmp[3] << 16);
      o.z = (unsigned int)tmp[4] | ((unsigned int)tmp[5] << 16);
      o.w = (unsigned int)tmp[6] | ((unsigned int)tmp[7] << 16);
      *(uint4*)&dst[(size_t)c * dstride + dcol0 + r0 + ru * 8] = o;
    }
  }
}

// ---- pos4: pack (x,y,z,|p|^2); pad w=+INF; zero counts/cursor/nfail; cell hist ----
__global__ __launch_bounds__(256) void pos4_kernel(
    const float* __restrict__ pos, float4* __restrict__ pos4,
    int* __restrict__ counts, int* __restrict__ cursor,
    int* __restrict__ cellid, int* __restrict__ cellcnt,
    int* __restrict__ nfail)
{
  int c = blockIdx.x * 256 + threadIdx.x;      // grid 40 -> 10240 threads
  if (c == 0) *nfail = 0;
  if (c < POS4_PAD) {
    float4 v;
    if (c < N_NODES) {
      float x = pos[c * 3 + 0], y = pos[c * 3 + 1], z = pos[c * 3 + 2];
      v = make_float4(x, y, z, x * x + y * y + z * z);
      int cx = min(15, max(0, (int)floorf((x + 4.0f) * 2.0f)));
      int cy = min(15, max(0, (int)floorf((y + 4.0f) * 2.0f)));
      int cz = min(15, max(0, (int)floorf((z + 4.0f) * 2.0f)));
      int cell = (cx << 8) | (cy << 4) | cz;
      cellid[c] = cell;
      atomicAdd(&cellcnt[cell], 1);
      counts[c] = 0; cursor[c] = 0;
    } else {
      v = make_float4(0.f, 0.f, 0.f, __builtin_inff());   // d -> +INF
    }
    pos4[c] = v;
  }
}

// cell-histogram exclusive scan: 1 block, 16 cells/thread
__global__ __launch_bounds__(256) void cellscan_kernel(
    const int* __restrict__ cellcnt, int* __restrict__ cellptr)
{
  __shared__ int part[256];
  const int tid = threadIdx.x;
  const int base = tid * 16;
  int cv[16];
  int s = 0;
#pragma unroll
  for (int q = 0; q < 4; ++q) {
    int4 v = *(const int4*)&cellcnt[base + q * 4];
    cv[q * 4 + 0] = v.x; cv[q * 4 + 1] = v.y;
    cv[q * 4 + 2] = v.z; cv[q * 4 + 3] = v.w;
    s += v.x + v.y + v.z + v.w;
  }
  part[tid] = s;
  __syncthreads();
  for (int off = 1; off < 256; off <<= 1) {
    int add = (tid >= off) ? part[tid - off] : 0;
    __syncthreads();
    part[tid] += add;
    __syncthreads();
  }
  int run = part[tid] - s;
#pragma unroll
  for (int q = 0; q < 16; ++q) { cellptr[base + q] = run; run += cv[q]; }
  if (tid == 255) cellptr[NCELL] = run;
}

// counting-sort scatter: perm (cell-grouped node ids) + pos4s (sorted coords)
__global__ __launch_bounds__(256) void perm_kernel(
    const int* __restrict__ cellid, const int* __restrict__ cellptr,
    int* __restrict__ cellcur, int* __restrict__ perm,
    const float4* __restrict__ pos4, float4* __restrict__ pos4s)
{
  int c = blockIdx.x * 256 + threadIdx.x;
  if (c < N_NODES) {
    int cell = cellid[c];
    int p = atomicAdd(&cellcur[cell], 1);
    int slot = cellptr[cell] + p;
    perm[slot] = c;
    pos4s[slot] = pos4[c];
  }
}

// identical expression everywhere -> bit-identical distances
__device__ __forceinline__ float knn_dist(float4 pi, float4 s) {
  float dot = fmaf(pi.x, s.x, fmaf(pi.y, s.y, pi.z * s.z));
  return fmaf(-2.0f, dot, pi.w + s.w);
}

__device__ __forceinline__ void insert8(float r[8], float k) {
  // r ascending; r_j = median(k, r_{j-1}, r_j)
  asm("v_med3_f32 %0, %1, %2, %3" : "=v"(r[7]) : "v"(k), "v"(r[6]), "v"(r[7]));
  asm("v_med3_f32 %0, %1, %2, %3" : "=v"(r[6]) : "v"(k), "v"(r[5]), "v"(r[6]));
  asm("v_med3_f32 %0, %1, %2, %3" : "=v"(r[5]) : "v"(k), "v"(r[4]), "v"(r[5]));
  asm("v_med3_f32 %0, %1, %2, %3" : "=v"(r[4]) : "v"(k), "v"(r[3]), "v"(r[4]));
  asm("v_med3_f32 %0, %1, %2, %3" : "=v"(r[3]) : "v"(k), "v"(r[2]), "v"(r[3]));
  asm("v_med3_f32 %0, %1, %2, %3" : "=v"(r[2]) : "v"(k), "v"(r[1]), "v"(r[2]));
  asm("v_med3_f32 %0, %1, %2, %3" : "=v"(r[1]) : "v"(k), "v"(r[0]), "v"(r[1]));
  r[0] = fminf(r[0], k);
}

__device__ __forceinline__ float merge_tau20(float r[8], int lane) {
  const float INF = __builtin_inff();
  float tau = INF;
#pragma unroll
  for (int t = 0; t < KNN_K; ++t) {
    float m = r[0];
    m = fminf(m, __shfl_xor(m, 1));
    m = fminf(m, __shfl_xor(m, 2));
    m = fminf(m, __shfl_xor(m, 4));
    m = fminf(m, __shfl_xor(m, 8));
    m = fminf(m, __shfl_xor(m, 16));
    m = fminf(m, __shfl_xor(m, 32));
    unsigned long long who = __ballot(r[0] == m);
    int srcl = __ffsll(who) - 1;
    if (lane == srcl) {
#pragma unroll
      for (int z = 0; z < 7; ++z) r[z] = r[z + 1];
      r[7] = INF;
    }
    tau = m;
  }
  return tau;   // exact 20th smallest (INF if <20 candidates)
}

__device__ __forceinline__ void emit_hits(
    int i, bool valid, float d, float tau, int cid, int lane, int& cnt,
    int* __restrict__ knn_out)
{
  unsigned long long less = __ballot(valid && d < tau);
  unsigned long long eq   = __ballot(valid && d == tau);
  if (less) {
    if (valid && d < tau) {
      int pos = cnt + (int)__popcll(less & ((1ull << lane) - 1ull));
      if (pos < KNN_K) knn_out[i * KNN_K + pos] = cid;
    }
    cnt += (int)__popcll(less);
  }
  if (eq && cnt < KNN_K) {
    if (valid && d == tau) {
      int pos = cnt + (int)__popcll(eq & ((1ull << lane) - 1ull));
      if (pos < KNN_K) knn_out[i * KNN_K + pos] = cid;
    }
    cnt = min(KNN_K, cnt + (int)__popcll(eq));
  }
}

// ---------------- kNN try: 3^3 grid-pruned exact (round-10 path); else worklist ----------------
__global__ __launch_bounds__(256) void knn_try_kernel(
    const float4* __restrict__ pos4, const float4* __restrict__ pos4s,
    const int* __restrict__ perm, const int* __restrict__ cellptr,
    int* __restrict__ knn_out, int* __restrict__ wl, int* __restrict__ nfail)
{
  const int lane = threadIdx.x & 63, wave = threadIdx.x >> 6;
  const int wid = blockIdx.x * 4 + wave;
  const int i = perm[wid];                         // perm-ordered queries: L2 locality
  const float4 pi = pos4[i];
  const float INF = __builtin_inff();

  const int cx = min(15, max(0, (int)floorf((pi.x + 4.0f) * 2.0f)));
  const int cy = min(15, max(0, (int)floorf((pi.y + 4.0f) * 2.0f)));
  const int cz = min(15, max(0, (int)floorf((pi.z + 4.0f) * 2.0f)));
  const int x0 = max(cx - 1, 0), x1 = min(cx + 1, 15);
  const int y0 = max(cy - 1, 0), y1 = min(cy + 1, 15);
  const int z0 = max(cz - 1, 0), z1 = min(cz + 1, 15);

  float r[8];
#pragma unroll
  for (int q = 0; q < 8; ++q) r[q] = INF;

  // phase A: top-8 over the <=27-cell block (z-contiguous ranges)
  for (int X = x0; X <= x1; ++X)
    for (int Y = y0; Y <= y1; ++Y) {
      const int cb = (X << 8) | (Y << 4);
      const int s0 = cellptr[cb + z0], s1 = cellptr[cb + z1 + 1];
      for (int c0 = s0; c0 < s1; c0 += 64) {
        const int slot = c0 + lane;
        const int idx = min(slot, s1 - 1);
        const float4 s = pos4s[idx];
        const int nid = perm[idx];
        float d = knn_dist(pi, s);
        float k = (slot < s1 && nid != i) ? d : INF;
        insert8(r, k);
      }
    }
  float tau = merge_tau20(r, lane);

  // exactness margin: distance from query to scanned-region boundary
  float mx = INF, my = INF, mz = INF;
  if (x0 > 0)  mx = pi.x - (x0 * 0.5f - 4.0f);
  if (x1 < 15) mx = fminf(mx, ((x1 + 1) * 0.5f - 4.0f) - pi.x);
  if (y0 > 0)  my = pi.y - (y0 * 0.5f - 4.0f);
  if (y1 < 15) my = fminf(my, ((y1 + 1) * 0.5f - 4.0f) - pi.y);
  if (z0 > 0)  mz = pi.z - (z0 * 0.5f - 4.0f);
  if (z1 < 15) mz = fminf(mz, ((z1 + 1) * 0.5f - 4.0f) - pi.z);
  const float marg = fminf(mx, fminf(my, mz));

  if (tau < marg * marg) {
    // accepted: ball(sqrt(tau)) inside scanned region -> exact neighbor set
    int cnt = 0;
    for (int X = x0; X <= x1; ++X)
      for (int Y = y0; Y <= y1; ++Y) {
        const int cb = (X << 8) | (Y << 4);
        const int s0 = cellptr[cb + z0], s1 = cellptr[cb + z1 + 1];
        for (int c0 = s0; c0 < s1; c0 += 64) {
          const int slot = c0 + lane;
          const int idx = min(slot, s1 - 1);
          const float4 s = pos4s[idx];
          const int nid = perm[idx];
          float d = knn_dist(pi, s);
          bool valid = (slot < s1) && (nid != i);
          emit_hits(i, valid, d, tau, nid, lane, cnt, knn_out);
        }
      }
    return;
  }

  // failed: defer to knn_full (round-6 exact full scan)
  if (lane == 0) {
    int slot = atomicAdd(nfail, 1);
    wl[slot] = i;
  }
}

// ---------------- kNN full scan for worklist queries (round-6 exact path) ----------------
__global__ __launch_bounds__(256) void knn_full_kernel(
    const float4* __restrict__ pos4, const int* __restrict__ wl,
    const int* __restrict__ nfail, int* __restrict__ knn_out)
{
  const int lane = threadIdx.x & 63, wave = threadIdx.x >> 6;
  const int w = blockIdx.x * 4 + wave;
  if (w >= *nfail) return;                         // no barriers below: safe
  const int i = wl[w];
  const float4 pi = pos4[i];
  const float INF = __builtin_inff();

  float r[8];
#pragma unroll
  for (int q = 0; q < 8; ++q) r[q] = INF;
#pragma unroll 4
  for (int b = 0; b < NBATCH; ++b) {
    const int cid = b * 64 + lane;
    const float4 s = pos4[cid];
    float d = knn_dist(pi, s);                    // pad rows: +INF
    float k = (cid == i) ? INF : d;
    insert8(r, k);
  }
  float tau = merge_tau20(r, lane);
  int cnt = 0;
  for (int b = 0; b < NBATCH; ++b) {
    const int cid = b * 64 + lane;
    const float4 s = pos4[cid];
    float d = knn_dist(pi, s);
    bool valid = (cid != i);
    emit_hits(i, valid, d, tau, cid, lane, cnt, knn_out);
  }
}

// ---------------- reverse-CSR build ----------------
__global__ __launch_bounds__(256) void count_kernel(
    const int* __restrict__ knn, int* __restrict__ counts)
{
  int e = blockIdx.x * 256 + threadIdx.x;
  if (e < NEDGE) atomicAdd(&counts[knn[e]], 1);
}

// node-degree exclusive scan (int4 loads; 250 threads x 40 exact)
__global__ __launch_bounds__(256) void scan_kernel(
    const int* __restrict__ counts, int* __restrict__ rptr)
{
  __shared__ int part[256];
  const int tid = threadIdx.x;
  const int base = tid * 40;                       // 250*40 = 10000 exact
  int s = 0;
  int cv[40];
  if (tid < 250) {
#pragma unroll
    for (int q = 0; q < 10; ++q) {
      int4 v = *(const int4*)&counts[base + q * 4];
      cv[q * 4 + 0] = v.x; cv[q * 4 + 1] = v.y;
      cv[q * 4 + 2] = v.z; cv[q * 4 + 3] = v.w;
      s += v.x + v.y + v.z + v.w;
    }
  }
  part[tid] = s;
  __syncthreads();
  for (int off = 1; off < 256; off <<= 1) {
    int add = (tid >= off) ? part[tid - off] : 0;
    __syncthreads();
    part[tid] += add;
    __syncthreads();
  }
  int run = part[tid] - s;                         // exclusive offset
  if (tid < 250) {
#pragma unroll
    for (int q = 0; q < 40; ++q) { rptr[base + q] = run; run += cv[q]; }
  }
  if (tid == 255) rptr[N_NODES] = run;
}

__global__ __launch_bounds__(256) void fill_kernel(
    const int* __restrict__ knn, const int* __restrict__ rptr,
    int* __restrict__ cursor, int* __restrict__ rsrc)
{
  int e = blockIdx.x * 256 + threadIdx.x;
  if (e < NEDGE) {
    int j = knn[e];
    int i = e / KNN_K;
    int p = atomicAdd(&cursor[j], 1);
    rsrc[rptr[j] + p] = i;
  }
}

// sort each reverse-adjacency list ascending (bitonic-64 per wave)
__global__ __launch_bounds__(256) void sort_kernel(
    const int* __restrict__ rptr, int* __restrict__ rsrc)
{
  const int lane = threadIdx.x & 63, wave = threadIdx.x >> 6;
  const int j = blockIdx.x * 4 + wave;
  const int s0 = rptr[j], s1 = rptr[j + 1], deg = s1 - s0;
  if (deg <= 64) {
    int v = (lane < deg) ? rsrc[s0 + lane] : 0x7FFFFFFF;
#pragma unroll
    for (int k = 2; k <= 64; k <<= 1) {
#pragma unroll
      for (int m = k >> 1; m > 0; m >>= 1) {
        int other = __shfl_xor(v, m);
        bool up = ((lane & k) == 0);
        bool lower = ((lane & m) == 0);
        v = (up == lower) ? min(v, other) : max(v, other);
      }
    }
    if (lane < deg) rsrc[s0 + lane] = v;
  } else if (lane == 0) {
    for (int a = s0 + 1; a < s1; ++a) {
      int v = rsrc[a];
      int b = a - 1;
      while (b >= s0 && rsrc[b] > v) { rsrc[b + 1] = rsrc[b]; --b; }
      rsrc[b + 1] = v;
    }
  }
}

// ---------------- prop: out[j] = scale2 * sum_{i in rev(j)} t[i] - prev[j] ----------------
// XCD-chunked spatial schedule (perm is cell-sorted -> L2-local gathers)
__global__ __launch_bounds__(256) void prop_kernel(
    const unsigned short* __restrict__ tin, const unsigned short* __restrict__ tprev,
    unsigned short* __restrict__ tout, const int* __restrict__ rptr,
    const int* __restrict__ rsrc, const int* __restrict__ perm, float scale2)
{
  const int wave = threadIdx.x >> 6, lane = threadIdx.x & 63;
  const int b = blockIdx.x;                        // grid 2504
  const int xcd = b & 7, qb = b >> 3;
  const int local = qb * 4 + wave;
  if (local >= NPX) return;                        // no barriers below: safe
  const int j = perm[xcd * NPX + local];
  const int s0 = rptr[j], s1 = rptr[j + 1];
  const size_t coff = (size_t)lane * 8;

  float a0[8], a1[8], a2[8], a3[8];
#pragma unroll
  for (int q = 0; q < 8; ++q) { a0[q] = 0.f; a1[q] = 0.f; a2[q] = 0.f; a3[q] = 0.f; }

  for (int base = s0; base < s1; base += 64) {
    const int clen = min(64, s1 - base);
    int myidx = (base + lane < s1) ? rsrc[base + lane] : 0;
    int t = 0;
    for (; t + 4 <= clen; t += 4) {
      int i0 = __shfl(myidx, t);
      int i1 = __shfl(myidx, t + 1);
      int i2 = __shfl(myidx, t + 2);
      int i3 = __shfl(myidx, t + 3);
      uint4 v0 = *(const uint4*)&tin[(size_t)i0 * 512 + coff];
      uint4 v1 = *(const uint4*)&tin[(size_t)i1 * 512 + coff];
      uint4 v2 = *(const uint4*)&tin[(size_t)i2 * 512 + coff];
      uint4 v3 = *(const uint4*)&tin[(size_t)i3 * 512 + coff];
      a0[0] += bf_lo(v0.x); a0[1] += bf_hi(v0.x); a0[2] += bf_lo(v0.y); a0[3] += bf_hi(v0.y);
      a0[4] += bf_lo(v0.z); a0[5] += bf_hi(v0.z); a0[6] += bf_lo(v0.w); a0[7] += bf_hi(v0.w);
      a1[0] += bf_lo(v1.x); a1[1] += bf_hi(v1.x); a1[2] += bf_lo(v1.y); a1[3] += bf_hi(v1.y);
      a1[4] += bf_lo(v1.z); a1[5] += bf_hi(v1.z); a1[6] += bf_lo(v1.w); a1[7] += bf_hi(v1.w);
      a2[0] += bf_lo(v2.x); a2[1] += bf_hi(v2.x); a2[2] += bf_lo(v2.y); a2[3] += bf_hi(v2.y);
      a2[4] += bf_lo(v2.z); a2[5] += bf_hi(v2.z); a2[6] += bf_lo(v2.w); a2[7] += bf_hi(v2.w);
      a3[0] += bf_lo(v3.x); a3[1] += bf_hi(v3.x); a3[2] += bf_lo(v3.y); a3[3] += bf_hi(v3.y);
      a3[4] += bf_lo(v3.z); a3[5] += bf_hi(v3.z); a3[6] += bf_lo(v3.w); a3[7] += bf_hi(v3.w);
    }
    for (; t < clen; ++t) {
      int i0 = __shfl(myidx, t);
      uint4 v0 = *(const uint4*)&tin[(size_t)i0 * 512 + coff];
      a0[0] += bf_lo(v0.x); a0[1] += bf_hi(v0.x); a0[2] += bf_lo(v0.y); a0[3] += bf_hi(v0.y);
      a0[4] += bf_lo(v0.z); a0[5] += bf_hi(v0.z); a0[6] += bf_lo(v0.w); a0[7] += bf_hi(v0.w);
    }
  }

  float pv[8] = {0.f, 0.f, 0.f, 0.f, 0.f, 0.f, 0.f, 0.f};
  if (tprev != nullptr) {
    uint4 p = *(const uint4*)&tprev[(size_t)j * 512 + coff];
    pv[0] = bf_lo(p.x); pv[1] = bf_hi(p.x);
    pv[2] = bf_lo(p.y); pv[3] = bf_hi(p.y);
    pv[4] = bf_lo(p.z); pv[5] = bf_hi(p.z);
    pv[6] = bf_lo(p.w); pv[7] = bf_hi(p.w);
  }
  unsigned short o16[8];
#pragma unroll
  for (int q = 0; q < 8; ++q) {
    float acc = (a0[q] + a1[q]) + (a2[q] + a3[q]);   // fixed tree, deterministic
    o16[q] = f2bf(scale2 * acc - pv[q]);
  }
  uint4 o;
  o.x = (unsigned int)o16[0] | ((unsigned int)o16[1] << 16);
  o.y = (unsigned int)o16[2] | ((unsigned int)o16[3] << 16);
  o.z = (unsigned int)o16[4] | ((unsigned int)o16[5] << 16);
  o.w = (unsigned int)o16[6] | ((unsigned int)o16[7] << 16);
  *(uint4*)&tout[(size_t)j * 512 + coff] = o;
}

// ---------------- GEMM: C[o][n] = sum_kc A[n][kc] * B[kc][o] + bias[o] ----------------
// Double-buffered LDS; T2 XOR swizzle (pre-swizzled global source, linear LDS
// dest, XOR'd read); XCD-chunked n-major 1-D grid (bijective m204 split).
__global__ __launch_bounds__(256) void gemm_kernel(
    const unsigned short* __restrict__ A,
    const unsigned short* __restrict__ Bt,
    const float* __restrict__ bias,
    float* __restrict__ C)
{
  __shared__ __align__(16) char smem[65536];          // 2 x (As 16KB + Bs 16KB)
  float* eps = (float*)smem;                          // epilogue [64 o][132] f32

  const int tid = threadIdx.x;
  const int wave = tid >> 6, lane = tid & 63;
  const int l15 = lane & 15, hi = lane >> 4;
  const int wr = wave >> 1, wc = wave & 1;

  // bijective XCD-chunked mapping of 316 (n,o) pairs, n-major
  const int bid = blockIdx.x;                         // 0..319
  const int xcd = bid & 7, local = bid >> 3;
  const int qd = GM_PAIRS >> 3, rem = GM_PAIRS & 7;   // 39, 4
  const int cnt = (xcd < rem) ? qd + 1 : qd;
  if (local >= cnt) return;                           // whole block exits: safe
  const int start = (xcd < rem) ? xcd * (qd + 1) : rem * (qd + 1) + (xcd - rem) * qd;
  const int pair = start + local;
  const int n0 = (pair >> 2) * 128;
  const int o0 = (pair & 3) * 128;

  f32x4 acc[4][4];
#pragma unroll
  for (int a = 0; a < 4; ++a)
#pragma unroll
    for (int b = 0; b < 4; ++b) acc[a][b] = (f32x4){0.f, 0.f, 0.f, 0.f};

  // stage K-tile kt into buffer sel. LDS dest linear (slot = unit idx);
  // global 16B-unit column pre-swizzled: u_g = u ^ (r&7).
  auto stage = [&](int kt, int sel) {
    const int k0 = kt * 64;
    const int ko = k0 >> 9;
    const int c0 = k0 & 511;
    const unsigned short* Ab = A + (size_t)ko * ((size_t)N_NODES * 512);
    unsigned short* As = (unsigned short*)(smem + sel * 32768);
    unsigned short* Bs = As + 128 * 64;
#pragma unroll
    for (int q = 0; q < 4; ++q) {
      int idx = (wave * 4 + q) * 64 + lane;           // 16B unit id, 0..1023
      int r = idx >> 3, u = idx & 7;
      int ug = u ^ (r & 7);
      gll16(Ab + (size_t)(n0 + r) * 512 + c0 + ug * 8, As + (size_t)(wave * 4 + q) * 512);
    }
#pragma unroll
    for (int q = 0; q < 4; ++q) {
      int idx = (wave * 4 + q) * 64 + lane;
      int r = idx >> 3, u = idx & 7;
      int ug = u ^ (r & 7);
      gll16(Bt + (size_t)(o0 + r) * 2560 + k0 + ug * 8, Bs + (size_t)(wave * 4 + q) * 512);
    }
  };

  stage(0, 0);
  __syncthreads();                                     // drains vmcnt(0)

  int cur = 0;
  for (int kt = 0; kt < 40; ++kt) {
    if (kt + 1 < 40) stage(kt + 1, cur ^ 1);           // prefetch flies under MFMA
    unsigned short* As = (unsigned short*)(smem + cur * 32768);
    unsigned short* Bs = As + 128 * 64;
#pragma unroll
    for (int kk = 0; kk < 2; ++kk) {
      bf16x8 af[4], bfr[4];
#pragma unroll
      for (int mi = 0; mi < 4; ++mi) {
        int row = wr * 64 + mi * 16 + l15;
        int up = (kk * 4 + hi) ^ (row & 7);            // read-side XOR
        af[mi] = *(const bf16x8*)(As + row * 64 + up * 8);
      }
#pragma unroll
      for (int ni = 0; ni < 4; ++ni) {
        int row = wc * 64 + ni * 16 + l15;
        int up = (kk * 4 + hi) ^ (row & 7);
        bfr[ni] = *(const bf16x8*)(Bs + row * 64 + up * 8);
      }
#pragma unroll
      for (int mi = 0; mi < 4; ++mi)
#pragma unroll
        for (int ni = 0; ni < 4; ++ni)
          acc[mi][ni] = __builtin_amdgcn_mfma_f32_16x16x32_bf16(af[mi], bfr[ni], acc[mi][ni], 0, 0, 0);
    }
    __syncthreads();                                   // next buffer complete
    cur ^= 1;
  }

  // epilogue: LDS-transposed coalesced store of C[o][n] + bias
#pragma unroll
  for (int h = 0; h < 2; ++h) {
    __syncthreads();
    if (wc == h) {
#pragma unroll
      for (int mi = 0; mi < 4; ++mi)
#pragma unroll
        for (int ni = 0; ni < 4; ++ni) {
          int o_l = ni * 16 + l15;                   // 0..63 within half
          int nb = wr * 64 + mi * 16 + hi * 4;       // 0..124, x4 aligned
          *(f32x4*)&eps[o_l * 132 + nb] = acc[mi][ni];
        }
    }
    __syncthreads();
#pragma unroll
    for (int q = 0; q < 8; ++q) {
      int unit = q * 256 + tid;                      // 2048 float4 units
      int o_l = unit >> 5, nu = unit & 31;
      int n = n0 + nu * 4;
      if (n < N_NODES) {
        int o = o0 + h * 64 + o_l;
        f32x4 v = *(const f32x4*)&eps[o_l * 132 + nu * 4];
        float bo = bias[o];
        v = v + bo;
        *(f32x4*)&C[(size_t)o * N_NODES + n] = v;
      }
    }
  }
}

extern "C" void kernel_launch(void* const* d_in, const int* in_sizes, int n_in,
                              void* d_out, int out_size, void* d_ws, size_t ws_size,
                              hipStream_t stream)
{
  const float* x        = (const float*)d_in[0];   // [512][10000]
  const float* position = (const float*)d_in[1];   // [10000][3]
  const float* theta    = (const float*)d_in[2];   // [5][512][512]
  const float* bias     = (const float*)d_in[3];   // [512]

  char* ws = (char*)d_ws;
  size_t off = 0;
  auto alloc = [&](size_t bytes) -> void* {
    void* p = ws + off;
    off = (off + bytes + 255) & ~(size_t)255;
    return p;
  };
  unsigned short* TxAll   = (unsigned short*)alloc(5ull * N_NODES * 512 * 2 + 131072); // +128-row pad
  unsigned short* thetabT = (unsigned short*)alloc(512ull * 2560 * 2);
  float4* pos4  = (float4*)alloc((size_t)POS4_PAD * 16);
  float4* pos4s = (float4*)alloc((size_t)N_NODES * 16);
  int* knn    = (int*)alloc((size_t)NEDGE * 4);
  int* rptr   = (int*)alloc((size_t)(N_NODES + 1) * 4);
  int* counts = (int*)alloc((size_t)N_NODES * 4);
  int* cursor = (int*)alloc((size_t)N_NODES * 4);
  int* rsrc   = (int*)alloc((size_t)NEDGE * 4);
  int* cellcnt = (int*)alloc((size_t)NCELL * 4);   // contiguous with cellcur:
  int* cellcur = (int*)alloc((size_t)NCELL * 4);   // one memset covers both
  int* cellptr = (int*)alloc((size_t)(NCELL + 1) * 4);
  int* cellid  = (int*)alloc((size_t)N_NODES * 4);
  int* perm    = (int*)alloc((size_t)N_NODES * 4);
  int* wl      = (int*)alloc((size_t)N_NODES * 4);
  int* nfail   = (int*)alloc(256);
  if (ws_size < off) return;   // insufficient scratch

  // theta [5][512][512] -> thetabT [o=512][kc=2560]
  transpose_f32_bf16<<<dim3(8, 8, 5), 256, 0, stream>>>(
      theta, thetabT, 512, 512, 2560, (size_t)512 * 512, 512);
  // x [512][10000] -> Tx0 [10000][512]
  transpose_f32_bf16<<<dim3(157, 8, 1), 256, 0, stream>>>(
      x, TxAll, 512, N_NODES, 512, 0, 0);

  hipMemsetAsync(cellcnt, 0, (size_t)((char*)cellptr - (char*)cellcnt), stream);
  pos4_kernel<<<40, 256, 0, stream>>>(position, pos4, counts, cursor, cellid, cellcnt, nfail);
  cellscan_kernel<<<1, 256, 0, stream>>>(cellcnt, cellptr);
  perm_kernel<<<40, 256, 0, stream>>>(cellid, cellptr, cellcur, perm, pos4, pos4s);

  knn_try_kernel<<<2500, 256, 0, stream>>>(pos4, pos4s, perm, cellptr, knn, wl, nfail);
  knn_full_kernel<<<2500, 256, 0, stream>>>(pos4, wl, nfail, knn);

  count_kernel<<<(NEDGE + 255) / 256, 256, 0, stream>>>(knn, counts);
  scan_kernel<<<1, 256, 0, stream>>>(counts, rptr);
  fill_kernel<<<(NEDGE + 255) / 256, 256, 0, stream>>>(knn, rptr, cursor, rsrc);
  sort_kernel<<<2500, 256, 0, stream>>>(rptr, rsrc);

  unsigned short* Tx0 = TxAll;
  unsigned short* Tx1 = TxAll + 1ull * N_NODES * 512;
  unsigned short* Tx2 = TxAll + 2ull * N_NODES * 512;
  unsigned short* Tx3 = TxAll + 3ull * N_NODES * 512;
  unsigned short* Tx4 = TxAll + 4ull * N_NODES * 512;

  // Tx1 = prop(Tx0) = -0.05*sum ; Tx_k = 2*prop(Tx_{k-1}) - Tx_{k-2} = -0.10*sum - prev
  prop_kernel<<<2504, 256, 0, stream>>>(Tx0, nullptr, Tx1, rptr, rsrc, perm, -0.05f);
  prop_kernel<<<2504, 256, 0, stream>>>(Tx1, Tx0,     Tx2, rptr, rsrc, perm, -0.10f);
  prop_kernel<<<2504, 256, 0, stream>>>(Tx2, Tx1,     Tx3, rptr, rsrc, perm, -0.10f);
  prop_kernel<<<2504, 256, 0, stream>>>(Tx3, Tx2,     Tx4, rptr, rsrc, perm, -0.10f);

  gemm_kernel<<<320, 256, 0, stream>>>(TxAll, thetabT, bias, (float*)d_out);
}

// Round 14
// 231.547 us; speedup vs baseline: 1.1580x; 1.0756x over previous
//
// Round 14: knn_full rewritten block-per-query (4 waves split the 157 batches;
// block-level exact tau via LDS; atomic-slot emit + sorted tie fill). Was 50us
// at 10% occupancy / 1 wave/SIMD (1050 queries x 1 wave = zero TLP).
// Everything else byte-identical to round-13 pass (249us).
#include <hip/hip_runtime.h>
#include <hip/hip_bf16.h>
#include <cstdint>
#include <cstddef>

#define N_NODES 10000
#define KNN_K 20
#define NEDGE (N_NODES * KNN_K)
#define NBATCH 157                 // ceil(10000/64)
#define POS4_PAD 10048             // 157*64
#define NCELL 4096                 // 16x16x16 spatial cells, h=0.5
#define NPX 1250                   // nodes per XCD chunk (10000/8)
#define GM_PAIRS 316               // 79 n-tiles x 4 o-tiles

using bf16x8 = __attribute__((ext_vector_type(8))) short;
using f32x4  = __attribute__((ext_vector_type(4))) float;

__device__ __forceinline__ float bf_lo(unsigned int u) {
  union { unsigned int i; float f; } c; c.i = u << 16; return c.f;
}
__device__ __forceinline__ float bf_hi(unsigned int u) {
  union { unsigned int i; float f; } c; c.i = u & 0xFFFF0000u; return c.f;
}
__device__ __forceinline__ unsigned short f2bf(float f) {
  union { float f; unsigned int i; } c; c.f = f;
  unsigned int u = c.i;
  u += 0x7FFFu + ((u >> 16) & 1u);   // RNE
  return (unsigned short)(u >> 16);
}

__device__ __forceinline__ void gll16(const void* g, void* l) {
  __builtin_amdgcn_global_load_lds(
      (const __attribute__((address_space(1))) unsigned int*)g,
      (__attribute__((address_space(3))) unsigned int*)l,
      16, 0, 0);
}

// ---------------- transpose f32 [srows][scols] -> bf16 dst[col][dcol0 + row] ----------------
__global__ __launch_bounds__(256) void transpose_f32_bf16(
    const float* __restrict__ src0, unsigned short* __restrict__ dst,
    int srows, int scols, int dstride, size_t slice_elems, int dcol_per_slice)
{
  __shared__ float lds[64 * 65];
  const int z = blockIdx.z;
  const float* src = src0 + (size_t)z * slice_elems;
  const int dcol0 = z * dcol_per_slice;
  const int c0 = blockIdx.x * 64;
  const int r0 = blockIdx.y * 64;
  const int tid = threadIdx.x;
#pragma unroll
  for (int q = 0; q < 4; ++q) {
    int unit = q * 256 + tid;            // 1024 float4 units
    int rr = unit >> 4;                  // 0..63
    int cu = unit & 15;                  // 0..15
    int r = r0 + rr, c = c0 + cu * 4;
    float4 v = make_float4(0.f, 0.f, 0.f, 0.f);
    if (r < srows && c + 3 < scols) v = *(const float4*)&src[(size_t)r * scols + c];
    lds[rr * 65 + cu * 4 + 0] = v.x;
    lds[rr * 65 + cu * 4 + 1] = v.y;
    lds[rr * 65 + cu * 4 + 2] = v.z;
    lds[rr * 65 + cu * 4 + 3] = v.w;
  }
  __syncthreads();
#pragma unroll
  for (int q = 0; q < 2; ++q) {
    int unit = q * 256 + tid;            // 512 units of 8 bf16
    int cl = unit >> 3;                  // src col within tile (= dst row)
    int ru = unit & 7;
    int c = c0 + cl;
    if (c < scols) {
      unsigned short tmp[8];
#pragma unroll
      for (int j = 0; j < 8; ++j) tmp[j] = f2bf(lds[(ru * 8 + j) * 65 + cl]);
      uint4 o;
      o.x = (unsigned int)tmp[0] | ((unsigned int)tmp[1] << 16);
      o.y = (unsigned int)tmp[2] | ((unsigned int)tmp[3] << 16);
      o.z = (unsigned int)tmp[4] | ((unsigned int)tmp[5] << 16);
      o.w = (unsigned int)tmp[6] | ((unsigned int)tmp[7] << 16);
      *(uint4*)&dst[(size_t)c * dstride + dcol0 + r0 + ru * 8] = o;
    }
  }
}

// ---- pos4: pack (x,y,z,|p|^2); pad w=+INF; zero counts/cursor/nfail; cell hist ----
__global__ __launch_bounds__(256) void pos4_kernel(
    const float* __restrict__ pos, float4* __restrict__ pos4,
    int* __restrict__ counts, int* __restrict__ cursor,
    int* __restrict__ cellid, int* __restrict__ cellcnt,
    int* __restrict__ nfail)
{
  int c = blockIdx.x * 256 + threadIdx.x;      // grid 40 -> 10240 threads
  if (c == 0) *nfail = 0;
  if (c < POS4_PAD) {
    float4 v;
    if (c < N_NODES) {
      float x = pos[c * 3 + 0], y = pos[c * 3 + 1], z = pos[c * 3 + 2];
      v = make_float4(x, y, z, x * x + y * y + z * z);
      int cx = min(15, max(0, (int)floorf((x + 4.0f) * 2.0f)));
      int cy = min(15, max(0, (int)floorf((y + 4.0f) * 2.0f)));
      int cz = min(15, max(0, (int)floorf((z + 4.0f) * 2.0f)));
      int cell = (cx << 8) | (cy << 4) | cz;
      cellid[c] = cell;
      atomicAdd(&cellcnt[cell], 1);
      counts[c] = 0; cursor[c] = 0;
    } else {
      v = make_float4(0.f, 0.f, 0.f, __builtin_inff());   // d -> +INF
    }
    pos4[c] = v;
  }
}

// cell-histogram exclusive scan: 1 block, 16 cells/thread
__global__ __launch_bounds__(256) void cellscan_kernel(
    const int* __restrict__ cellcnt, int* __restrict__ cellptr)
{
  __shared__ int part[256];
  const int tid = threadIdx.x;
  const int base = tid * 16;
  int cv[16];
  int s = 0;
#pragma unroll
  for (int q = 0; q < 4; ++q) {
    int4 v = *(const int4*)&cellcnt[base + q * 4];
    cv[q * 4 + 0] = v.x; cv[q * 4 + 1] = v.y;
    cv[q * 4 + 2] = v.z; cv[q * 4 + 3] = v.w;
    s += v.x + v.y + v.z + v.w;
  }
  part[tid] = s;
  __syncthreads();
  for (int off = 1; off < 256; off <<= 1) {
    int add = (tid >= off) ? part[tid - off] : 0;
    __syncthreads();
    part[tid] += add;
    __syncthreads();
  }
  int run = part[tid] - s;
#pragma unroll
  for (int q = 0; q < 16; ++q) { cellptr[base + q] = run; run += cv[q]; }
  if (tid == 255) cellptr[NCELL] = run;
}

// counting-sort scatter: perm (cell-grouped node ids) + pos4s (sorted coords)
__global__ __launch_bounds__(256) void perm_kernel(
    const int* __restrict__ cellid, const int* __restrict__ cellptr,
    int* __restrict__ cellcur, int* __restrict__ perm,
    const float4* __restrict__ pos4, float4* __restrict__ pos4s)
{
  int c = blockIdx.x * 256 + threadIdx.x;
  if (c < N_NODES) {
    int cell = cellid[c];
    int p = atomicAdd(&cellcur[cell], 1);
    int slot = cellptr[cell] + p;
    perm[slot] = c;
    pos4s[slot] = pos4[c];
  }
}

// identical expression everywhere -> bit-identical distances
__device__ __forceinline__ float knn_dist(float4 pi, float4 s) {
  float dot = fmaf(pi.x, s.x, fmaf(pi.y, s.y, pi.z * s.z));
  return fmaf(-2.0f, dot, pi.w + s.w);
}

__device__ __forceinline__ void insert8(float r[8], float k) {
  // r ascending; r_j = median(k, r_{j-1}, r_j)
  asm("v_med3_f32 %0, %1, %2, %3" : "=v"(r[7]) : "v"(k), "v"(r[6]), "v"(r[7]));
  asm("v_med3_f32 %0, %1, %2, %3" : "=v"(r[6]) : "v"(k), "v"(r[5]), "v"(r[6]));
  asm("v_med3_f32 %0, %1, %2, %3" : "=v"(r[5]) : "v"(k), "v"(r[4]), "v"(r[5]));
  asm("v_med3_f32 %0, %1, %2, %3" : "=v"(r[4]) : "v"(k), "v"(r[3]), "v"(r[4]));
  asm("v_med3_f32 %0, %1, %2, %3" : "=v"(r[3]) : "v"(k), "v"(r[2]), "v"(r[3]));
  asm("v_med3_f32 %0, %1, %2, %3" : "=v"(r[2]) : "v"(k), "v"(r[1]), "v"(r[2]));
  asm("v_med3_f32 %0, %1, %2, %3" : "=v"(r[1]) : "v"(k), "v"(r[0]), "v"(r[1]));
  r[0] = fminf(r[0], k);
}

__device__ __forceinline__ float merge_tau20(float r[8], int lane) {
  const float INF = __builtin_inff();
  float tau = INF;
#pragma unroll
  for (int t = 0; t < KNN_K; ++t) {
    float m = r[0];
    m = fminf(m, __shfl_xor(m, 1));
    m = fminf(m, __shfl_xor(m, 2));
    m = fminf(m, __shfl_xor(m, 4));
    m = fminf(m, __shfl_xor(m, 8));
    m = fminf(m, __shfl_xor(m, 16));
    m = fminf(m, __shfl_xor(m, 32));
    unsigned long long who = __ballot(r[0] == m);
    int srcl = __ffsll(who) - 1;
    if (lane == srcl) {
#pragma unroll
      for (int z = 0; z < 7; ++z) r[z] = r[z + 1];
      r[7] = INF;
    }
    tau = m;
  }
  return tau;   // exact 20th smallest (INF if <20 candidates)
}

__device__ __forceinline__ void emit_hits(
    int i, bool valid, float d, float tau, int cid, int lane, int& cnt,
    int* __restrict__ knn_out)
{
  unsigned long long less = __ballot(valid && d < tau);
  unsigned long long eq   = __ballot(valid && d == tau);
  if (less) {
    if (valid && d < tau) {
      int pos = cnt + (int)__popcll(less & ((1ull << lane) - 1ull));
      if (pos < KNN_K) knn_out[i * KNN_K + pos] = cid;
    }
    cnt += (int)__popcll(less);
  }
  if (eq && cnt < KNN_K) {
    if (valid && d == tau) {
      int pos = cnt + (int)__popcll(eq & ((1ull << lane) - 1ull));
      if (pos < KNN_K) knn_out[i * KNN_K + pos] = cid;
    }
    cnt = min(KNN_K, cnt + (int)__popcll(eq));
  }
}

// ---------------- kNN try: 3^3 grid-pruned exact (round-10 path); else worklist ----------------
__global__ __launch_bounds__(256) void knn_try_kernel(
    const float4* __restrict__ pos4, const float4* __restrict__ pos4s,
    const int* __restrict__ perm, const int* __restrict__ cellptr,
    int* __restrict__ knn_out, int* __restrict__ wl, int* __restrict__ nfail)
{
  const int lane = threadIdx.x & 63, wave = threadIdx.x >> 6;
  const int wid = blockIdx.x * 4 + wave;
  const int i = perm[wid];                         // perm-ordered queries: L2 locality
  const float4 pi = pos4[i];
  const float INF = __builtin_inff();

  const int cx = min(15, max(0, (int)floorf((pi.x + 4.0f) * 2.0f)));
  const int cy = min(15, max(0, (int)floorf((pi.y + 4.0f) * 2.0f)));
  const int cz = min(15, max(0, (int)floorf((pi.z + 4.0f) * 2.0f)));
  const int x0 = max(cx - 1, 0), x1 = min(cx + 1, 15);
  const int y0 = max(cy - 1, 0), y1 = min(cy + 1, 15);
  const int z0 = max(cz - 1, 0), z1 = min(cz + 1, 15);

  float r[8];
#pragma unroll
  for (int q = 0; q < 8; ++q) r[q] = INF;

  // phase A: top-8 over the <=27-cell block (z-contiguous ranges)
  for (int X = x0; X <= x1; ++X)
    for (int Y = y0; Y <= y1; ++Y) {
      const int cb = (X << 8) | (Y << 4);
      const int s0 = cellptr[cb + z0], s1 = cellptr[cb + z1 + 1];
      for (int c0 = s0; c0 < s1; c0 += 64) {
        const int slot = c0 + lane;
        const int idx = min(slot, s1 - 1);
        const float4 s = pos4s[idx];
        const int nid = perm[idx];
        float d = knn_dist(pi, s);
        float k = (slot < s1 && nid != i) ? d : INF;
        insert8(r, k);
      }
    }
  float tau = merge_tau20(r, lane);

  // exactness margin: distance from query to scanned-region boundary
  float mx = INF, my = INF, mz = INF;
  if (x0 > 0)  mx = pi.x - (x0 * 0.5f - 4.0f);
  if (x1 < 15) mx = fminf(mx, ((x1 + 1) * 0.5f - 4.0f) - pi.x);
  if (y0 > 0)  my = pi.y - (y0 * 0.5f - 4.0f);
  if (y1 < 15) my = fminf(my, ((y1 + 1) * 0.5f - 4.0f) - pi.y);
  if (z0 > 0)  mz = pi.z - (z0 * 0.5f - 4.0f);
  if (z1 < 15) mz = fminf(mz, ((z1 + 1) * 0.5f - 4.0f) - pi.z);
  const float marg = fminf(mx, fminf(my, mz));

  if (tau < marg * marg) {
    // accepted: ball(sqrt(tau)) inside scanned region -> exact neighbor set
    int cnt = 0;
    for (int X = x0; X <= x1; ++X)
      for (int Y = y0; Y <= y1; ++Y) {
        const int cb = (X << 8) | (Y << 4);
        const int s0 = cellptr[cb + z0], s1 = cellptr[cb + z1 + 1];
        for (int c0 = s0; c0 < s1; c0 += 64) {
          const int slot = c0 + lane;
          const int idx = min(slot, s1 - 1);
          const float4 s = pos4s[idx];
          const int nid = perm[idx];
          float d = knn_dist(pi, s);
          bool valid = (slot < s1) && (nid != i);
          emit_hits(i, valid, d, tau, nid, lane, cnt, knn_out);
        }
      }
    return;
  }

  // failed: defer to knn_full (round-6 exact full scan)
  if (lane == 0) {
    int slot = atomicAdd(nfail, 1);
    wl[slot] = i;
  }
}

// ---------------- kNN full scan, block-per-query: 4 waves split the batches ----------------
__global__ __launch_bounds__(256) void knn_full_kernel(
    const float4* __restrict__ pos4, const int* __restrict__ wl,
    const int* __restrict__ nfail, int* __restrict__ knn_out)
{
  __shared__ float wmin[4];
  __shared__ int lcnt, eqcnt;
  __shared__ int eqbuf[64];
  const int tid = threadIdx.x;
  const int lane = tid & 63, wave = tid >> 6;
  const float INF = __builtin_inff();
  const int nf = *nfail;

  for (int w = blockIdx.x; w < nf; w += 2500) {
    const int i = wl[w];
    const float4 pi = pos4[i];

    // phase 1: wave `wave` scans batches b ≡ wave (mod 4); per-lane top-8
    float r[8];
#pragma unroll
    for (int q = 0; q < 8; ++q) r[q] = INF;
    for (int b = wave; b < NBATCH; b += 4) {
      const int cid = b * 64 + lane;
      const float4 s = pos4[cid];
      float d = knn_dist(pi, s);                  // pad rows: +INF
      float k = (cid == i) ? INF : d;
      insert8(r, k);
    }

    // block-level exact tau: 20 extract-min rounds across 4 waves
    float tau = INF;
#pragma unroll
    for (int t = 0; t < KNN_K; ++t) {
      float m = r[0];
      m = fminf(m, __shfl_xor(m, 1));
      m = fminf(m, __shfl_xor(m, 2));
      m = fminf(m, __shfl_xor(m, 4));
      m = fminf(m, __shfl_xor(m, 8));
      m = fminf(m, __shfl_xor(m, 16));
      m = fminf(m, __shfl_xor(m, 32));
      if (lane == 0) wmin[wave] = m;
      __syncthreads();
      float m0 = wmin[0], m1 = wmin[1], m2 = wmin[2], m3 = wmin[3];
      float gm = fminf(fminf(m0, m1), fminf(m2, m3));
      int wsel = (m0 == gm) ? 0 : ((m1 == gm) ? 1 : ((m2 == gm) ? 2 : 3));
      __syncthreads();                             // wmin consumed; safe for next round
      if (wave == wsel) {
        unsigned long long who = __ballot(r[0] == gm);
        int srcl = __ffsll(who) - 1;               // non-empty: wsel's min == gm
        if (lane == srcl) {
#pragma unroll
          for (int z = 0; z < 7; ++z) r[z] = r[z + 1];
          r[7] = INF;
        }
      }
      tau = gm;
    }

    // phase 2: emit. d<tau -> atomic unique slots (set-exact, order-free);
    // d==tau ties -> collect, sort by id, lowest-first fill to 20.
    if (tid == 0) { lcnt = 0; eqcnt = 0; }
    __syncthreads();
    for (int b = wave; b < NBATCH; b += 4) {
      const int cid = b * 64 + lane;
      const float4 s = pos4[cid];
      float d = knn_dist(pi, s);
      bool valid = (cid != i);                     // pad rows: d=INF, never accepted
      if (valid && d < tau) {
        int slot = atomicAdd(&lcnt, 1);
        if (slot < KNN_K) knn_out[i * KNN_K + slot] = cid;
      }
      if (valid && d == tau) {
        int e = atomicAdd(&eqcnt, 1);
        if (e < 64) eqbuf[e] = cid;
      }
    }
    __syncthreads();
    if (tid == 0) {
      int base = lcnt;                             // <= 19 (tau = 20th smallest)
      int ne = min(eqcnt, 64);
      for (int a = 1; a < ne; ++a) {               // tiny insertion sort by id
        int v = eqbuf[a];
        int b2 = a - 1;
        while (b2 >= 0 && eqbuf[b2] > v) { eqbuf[b2 + 1] = eqbuf[b2]; --b2; }
        eqbuf[b2 + 1] = v;
      }
      for (int q = 0; q < ne && base + q < KNN_K; ++q)
        knn_out[i * KNN_K + base + q] = eqbuf[q];
    }
    __syncthreads();                               // lcnt/eqcnt reused next iter
  }
}

// ---------------- reverse-CSR build ----------------
__global__ __launch_bounds__(256) void count_kernel(
    const int* __restrict__ knn, int* __restrict__ counts)
{
  int e = blockIdx.x * 256 + threadIdx.x;
  if (e < NEDGE) atomicAdd(&counts[knn[e]], 1);
}

// node-degree exclusive scan (int4 loads; 250 threads x 40 exact)
__global__ __launch_bounds__(256) void scan_kernel(
    const int* __restrict__ counts, int* __restrict__ rptr)
{
  __shared__ int part[256];
  const int tid = threadIdx.x;
  const int base = tid * 40;                       // 250*40 = 10000 exact
  int s = 0;
  int cv[40];
  if (tid < 250) {
#pragma unroll
    for (int q = 0; q < 10; ++q) {
      int4 v = *(const int4*)&counts[base + q * 4];
      cv[q * 4 + 0] = v.x; cv[q * 4 + 1] = v.y;
      cv[q * 4 + 2] = v.z; cv[q * 4 + 3] = v.w;
      s += v.x + v.y + v.z + v.w;
    }
  }
  part[tid] = s;
  __syncthreads();
  for (int off = 1; off < 256; off <<= 1) {
    int add = (tid >= off) ? part[tid - off] : 0;
    __syncthreads();
    part[tid] += add;
    __syncthreads();
  }
  int run = part[tid] - s;                         // exclusive offset
  if (tid < 250) {
#pragma unroll
    for (int q = 0; q < 40; ++q) { rptr[base + q] = run; run += cv[q]; }
  }
  if (tid == 255) rptr[N_NODES] = run;
}

__global__ __launch_bounds__(256) void fill_kernel(
    const int* __restrict__ knn, const int* __restrict__ rptr,
    int* __restrict__ cursor, int* __restrict__ rsrc)
{
  int e = blockIdx.x * 256 + threadIdx.x;
  if (e < NEDGE) {
    int j = knn[e];
    int i = e / KNN_K;
    int p = atomicAdd(&cursor[j], 1);
    rsrc[rptr[j] + p] = i;
  }
}

// sort each reverse-adjacency list ascending (bitonic-64 per wave)
__global__ __launch_bounds__(256) void sort_kernel(
    const int* __restrict__ rptr, int* __restrict__ rsrc)
{
  const int lane = threadIdx.x & 63, wave = threadIdx.x >> 6;
  const int j = blockIdx.x * 4 + wave;
  const int s0 = rptr[j], s1 = rptr[j + 1], deg = s1 - s0;
  if (deg <= 64) {
    int v = (lane < deg) ? rsrc[s0 + lane] : 0x7FFFFFFF;
#pragma unroll
    for (int k = 2; k <= 64; k <<= 1) {
#pragma unroll
      for (int m = k >> 1; m > 0; m >>= 1) {
        int other = __shfl_xor(v, m);
        bool up = ((lane & k) == 0);
        bool lower = ((lane & m) == 0);
        v = (up == lower) ? min(v, other) : max(v, other);
      }
    }
    if (lane < deg) rsrc[s0 + lane] = v;
  } else if (lane == 0) {
    for (int a = s0 + 1; a < s1; ++a) {
      int v = rsrc[a];
      int b = a - 1;
      while (b >= s0 && rsrc[b] > v) { rsrc[b + 1] = rsrc[b]; --b; }
      rsrc[b + 1] = v;
    }
  }
}

// ---------------- prop: out[j] = scale2 * sum_{i in rev(j)} t[i] - prev[j] ----------------
// XCD-chunked spatial schedule (perm is cell-sorted -> L2-local gathers)
__global__ __launch_bounds__(256) void prop_kernel(
    const unsigned short* __restrict__ tin, const unsigned short* __restrict__ tprev,
    unsigned short* __restrict__ tout, const int* __restrict__ rptr,
    const int* __restrict__ rsrc, const int* __restrict__ perm, float scale2)
{
  const int wave = threadIdx.x >> 6, lane = threadIdx.x & 63;
  const int b = blockIdx.x;                        // grid 2504
  const int xcd = b & 7, qb = b >> 3;
  const int local = qb * 4 + wave;
  if (local >= NPX) return;                        // no barriers below: safe
  const int j = perm[xcd * NPX + local];
  const int s0 = rptr[j], s1 = rptr[j + 1];
  const size_t coff = (size_t)lane * 8;

  float a0[8], a1[8], a2[8], a3[8];
#pragma unroll
  for (int q = 0; q < 8; ++q) { a0[q] = 0.f; a1[q] = 0.f; a2[q] = 0.f; a3[q] = 0.f; }

  for (int base = s0; base < s1; base += 64) {
    const int clen = min(64, s1 - base);
    int myidx = (base + lane < s1) ? rsrc[base + lane] : 0;
    int t = 0;
    for (; t + 4 <= clen; t += 4) {
      int i0 = __shfl(myidx, t);
      int i1 = __shfl(myidx, t + 1);
      int i2 = __shfl(myidx, t + 2);
      int i3 = __shfl(myidx, t + 3);
      uint4 v0 = *(const uint4*)&tin[(size_t)i0 * 512 + coff];
      uint4 v1 = *(const uint4*)&tin[(size_t)i1 * 512 + coff];
      uint4 v2 = *(const uint4*)&tin[(size_t)i2 * 512 + coff];
      uint4 v3 = *(const uint4*)&tin[(size_t)i3 * 512 + coff];
      a0[0] += bf_lo(v0.x); a0[1] += bf_hi(v0.x); a0[2] += bf_lo(v0.y); a0[3] += bf_hi(v0.y);
      a0[4] += bf_lo(v0.z); a0[5] += bf_hi(v0.z); a0[6] += bf_lo(v0.w); a0[7] += bf_hi(v0.w);
      a1[0] += bf_lo(v1.x); a1[1] += bf_hi(v1.x); a1[2] += bf_lo(v1.y); a1[3] += bf_hi(v1.y);
      a1[4] += bf_lo(v1.z); a1[5] += bf_hi(v1.z); a1[6] += bf_lo(v1.w); a1[7] += bf_hi(v1.w);
      a2[0] += bf_lo(v2.x); a2[1] += bf_hi(v2.x); a2[2] += bf_lo(v2.y); a2[3] += bf_hi(v2.y);
      a2[4] += bf_lo(v2.z); a2[5] += bf_hi(v2.z); a2[6] += bf_lo(v2.w); a2[7] += bf_hi(v2.w);
      a3[0] += bf_lo(v3.x); a3[1] += bf_hi(v3.x); a3[2] += bf_lo(v3.y); a3[3] += bf_hi(v3.y);
      a3[4] += bf_lo(v3.z); a3[5] += bf_hi(v3.z); a3[6] += bf_lo(v3.w); a3[7] += bf_hi(v3.w);
    }
    for (; t < clen; ++t) {
      int i0 = __shfl(myidx, t);
      uint4 v0 = *(const uint4*)&tin[(size_t)i0 * 512 + coff];
      a0[0] += bf_lo(v0.x); a0[1] += bf_hi(v0.x); a0[2] += bf_lo(v0.y); a0[3] += bf_hi(v0.y);
      a0[4] += bf_lo(v0.z); a0[5] += bf_hi(v0.z); a0[6] += bf_lo(v0.w); a0[7] += bf_hi(v0.w);
    }
  }

  float pv[8] = {0.f, 0.f, 0.f, 0.f, 0.f, 0.f, 0.f, 0.f};
  if (tprev != nullptr) {
    uint4 p = *(const uint4*)&tprev[(size_t)j * 512 + coff];
    pv[0] = bf_lo(p.x); pv[1] = bf_hi(p.x);
    pv[2] = bf_lo(p.y); pv[3] = bf_hi(p.y);
    pv[4] = bf_lo(p.z); pv[5] = bf_hi(p.z);
    pv[6] = bf_lo(p.w); pv[7] = bf_hi(p.w);
  }
  unsigned short o16[8];
#pragma unroll
  for (int q = 0; q < 8; ++q) {
    float acc = (a0[q] + a1[q]) + (a2[q] + a3[q]);   // fixed tree, deterministic
    o16[q] = f2bf(scale2 * acc - pv[q]);
  }
  uint4 o;
  o.x = (unsigned int)o16[0] | ((unsigned int)o16[1] << 16);
  o.y = (unsigned int)o16[2] | ((unsigned int)o16[3] << 16);
  o.z = (unsigned int)o16[4] | ((unsigned int)o16[5] << 16);
  o.w = (unsigned int)o16[6] | ((unsigned int)o16[7] << 16);
  *(uint4*)&tout[(size_t)j * 512 + coff] = o;
}

// ---------------- GEMM: C[o][n] = sum_kc A[n][kc] * B[kc][o] + bias[o] ----------------
// Double-buffered LDS; T2 XOR swizzle (pre-swizzled global source, linear LDS
// dest, XOR'd read); XCD-chunked n-major 1-D grid (bijective m204 split).
__global__ __launch_bounds__(256) void gemm_kernel(
    const unsigned short* __restrict__ A,
    const unsigned short* __restrict__ Bt,
    const float* __restrict__ bias,
    float* __restrict__ C)
{
  __shared__ __align__(16) char smem[65536];          // 2 x (As 16KB + Bs 16KB)
  float* eps = (float*)smem;                          // epilogue [64 o][132] f32

  const int tid = threadIdx.x;
  const int wave = tid >> 6, lane = tid & 63;
  const int l15 = lane & 15, hi = lane >> 4;
  const int wr = wave >> 1, wc = wave & 1;

  // bijective XCD-chunked mapping of 316 (n,o) pairs, n-major
  const int bid = blockIdx.x;                         // 0..319
  const int xcd = bid & 7, local = bid >> 3;
  const int qd = GM_PAIRS >> 3, rem = GM_PAIRS & 7;   // 39, 4
  const int cnt = (xcd < rem) ? qd + 1 : qd;
  if (local >= cnt) return;                           // whole block exits: safe
  const int start = (xcd < rem) ? xcd * (qd + 1) : rem * (qd + 1) + (xcd - rem) * qd;
  const int pair = start + local;
  const int n0 = (pair >> 2) * 128;
  const int o0 = (pair & 3) * 128;

  f32x4 acc[4][4];
#pragma unroll
  for (int a = 0; a < 4; ++a)
#pragma unroll
    for (int b = 0; b < 4; ++b) acc[a][b] = (f32x4){0.f, 0.f, 0.f, 0.f};

  // stage K-tile kt into buffer sel. LDS dest linear (slot = unit idx);
  // global 16B-unit column pre-swizzled: u_g = u ^ (r&7).
  auto stage = [&](int kt, int sel) {
    const int k0 = kt * 64;
    const int ko = k0 >> 9;
    const int c0 = k0 & 511;
    const unsigned short* Ab = A + (size_t)ko * ((size_t)N_NODES * 512);
    unsigned short* As = (unsigned short*)(smem + sel * 32768);
    unsigned short* Bs = As + 128 * 64;
#pragma unroll
    for (int q = 0; q < 4; ++q) {
      int idx = (wave * 4 + q) * 64 + lane;           // 16B unit id, 0..1023
      int r = idx >> 3, u = idx & 7;
      int ug = u ^ (r & 7);
      gll16(Ab + (size_t)(n0 + r) * 512 + c0 + ug * 8, As + (size_t)(wave * 4 + q) * 512);
    }
#pragma unroll
    for (int q = 0; q < 4; ++q) {
      int idx = (wave * 4 + q) * 64 + lane;
      int r = idx >> 3, u = idx & 7;
      int ug = u ^ (r & 7);
      gll16(Bt + (size_t)(o0 + r) * 2560 + k0 + ug * 8, Bs + (size_t)(wave * 4 + q) * 512);
    }
  };

  stage(0, 0);
  __syncthreads();                                     // drains vmcnt(0)

  int cur = 0;
  for (int kt = 0; kt < 40; ++kt) {
    if (kt + 1 < 40) stage(kt + 1, cur ^ 1);           // prefetch flies under MFMA
    unsigned short* As = (unsigned short*)(smem + cur * 32768);
    unsigned short* Bs = As + 128 * 64;
#pragma unroll
    for (int kk = 0; kk < 2; ++kk) {
      bf16x8 af[4], bfr[4];
#pragma unroll
      for (int mi = 0; mi < 4; ++mi) {
        int row = wr * 64 + mi * 16 + l15;
        int up = (kk * 4 + hi) ^ (row & 7);            // read-side XOR
        af[mi] = *(const bf16x8*)(As + row * 64 + up * 8);
      }
#pragma unroll
      for (int ni = 0; ni < 4; ++ni) {
        int row = wc * 64 + ni * 16 + l15;
        int up = (kk * 4 + hi) ^ (row & 7);
        bfr[ni] = *(const bf16x8*)(Bs + row * 64 + up * 8);
      }
#pragma unroll
      for (int mi = 0; mi < 4; ++mi)
#pragma unroll
        for (int ni = 0; ni < 4; ++ni)
          acc[mi][ni] = __builtin_amdgcn_mfma_f32_16x16x32_bf16(af[mi], bfr[ni], acc[mi][ni], 0, 0, 0);
    }
    __syncthreads();                                   // next buffer complete
    cur ^= 1;
  }

  // epilogue: LDS-transposed coalesced store of C[o][n] + bias
#pragma unroll
  for (int h = 0; h < 2; ++h) {
    __syncthreads();
    if (wc == h) {
#pragma unroll
      for (int mi = 0; mi < 4; ++mi)
#pragma unroll
        for (int ni = 0; ni < 4; ++ni) {
          int o_l = ni * 16 + l15;                   // 0..63 within half
          int nb = wr * 64 + mi * 16 + hi * 4;       // 0..124, x4 aligned
          *(f32x4*)&eps[o_l * 132 + nb] = acc[mi][ni];
        }
    }
    __syncthreads();
#pragma unroll
    for (int q = 0; q < 8; ++q) {
      int unit = q * 256 + tid;                      // 2048 float4 units
      int o_l = unit >> 5, nu = unit & 31;
      int n = n0 + nu * 4;
      if (n < N_NODES) {
        int o = o0 + h * 64 + o_l;
        f32x4 v = *(const f32x4*)&eps[o_l * 132 + nu * 4];
        float bo = bias[o];
        v = v + bo;
        *(f32x4*)&C[(size_t)o * N_NODES + n] = v;
      }
    }
  }
}

extern "C" void kernel_launch(void* const* d_in, const int* in_sizes, int n_in,
                              void* d_out, int out_size, void* d_ws, size_t ws_size,
                              hipStream_t stream)
{
  const float* x        = (const float*)d_in[0];   // [512][10000]
  const float* position = (const float*)d_in[1];   // [10000][3]
  const float* theta    = (const float*)d_in[2];   // [5][512][512]
  const float* bias     = (const float*)d_in[3];   // [512]

  char* ws = (char*)d_ws;
  size_t off = 0;
  auto alloc = [&](size_t bytes) -> void* {
    void* p = ws + off;
    off = (off + bytes + 255) & ~(size_t)255;
    return p;
  };
  unsigned short* TxAll   = (unsigned short*)alloc(5ull * N_NODES * 512 * 2 + 131072); // +128-row pad
  unsigned short* thetabT = (unsigned short*)alloc(512ull * 2560 * 2);
  float4* pos4  = (float4*)alloc((size_t)POS4_PAD * 16);
  float4* pos4s = (float4*)alloc((size_t)N_NODES * 16);
  int* knn    = (int*)alloc((size_t)NEDGE * 4);
  int* rptr   = (int*)alloc((size_t)(N_NODES + 1) * 4);
  int* counts = (int*)alloc((size_t)N_NODES * 4);
  int* cursor = (int*)alloc((size_t)N_NODES * 4);
  int* rsrc   = (int*)alloc((size_t)NEDGE * 4);
  int* cellcnt = (int*)alloc((size_t)NCELL * 4);   // contiguous with cellcur:
  int* cellcur = (int*)alloc((size_t)NCELL * 4);   // one memset covers both
  int* cellptr = (int*)alloc((size_t)(NCELL + 1) * 4);
  int* cellid  = (int*)alloc((size_t)N_NODES * 4);
  int* perm    = (int*)alloc((size_t)N_NODES * 4);
  int* wl      = (int*)alloc((size_t)N_NODES * 4);
  int* nfail   = (int*)alloc(256);
  if (ws_size < off) return;   // insufficient scratch

  // theta [5][512][512] -> thetabT [o=512][kc=2560]
  transpose_f32_bf16<<<dim3(8, 8, 5), 256, 0, stream>>>(
      theta, thetabT, 512, 512, 2560, (size_t)512 * 512, 512);
  // x [512][10000] -> Tx0 [10000][512]
  transpose_f32_bf16<<<dim3(157, 8, 1), 256, 0, stream>>>(
      x, TxAll, 512, N_NODES, 512, 0, 0);

  hipMemsetAsync(cellcnt, 0, (size_t)((char*)cellptr - (char*)cellcnt), stream);
  pos4_kernel<<<40, 256, 0, stream>>>(position, pos4, counts, cursor, cellid, cellcnt, nfail);
  cellscan_kernel<<<1, 256, 0, stream>>>(cellcnt, cellptr);
  perm_kernel<<<40, 256, 0, stream>>>(cellid, cellptr, cellcur, perm, pos4, pos4s);

  knn_try_kernel<<<2500, 256, 0, stream>>>(pos4, pos4s, perm, cellptr, knn, wl, nfail);
  knn_full_kernel<<<2500, 256, 0, stream>>>(pos4, wl, nfail, knn);

  count_kernel<<<(NEDGE + 255) / 256, 256, 0, stream>>>(knn, counts);
  scan_kernel<<<1, 256, 0, stream>>>(counts, rptr);
  fill_kernel<<<(NEDGE + 255) / 256, 256, 0, stream>>>(knn, rptr, cursor, rsrc);
  sort_kernel<<<2500, 256, 0, stream>>>(rptr, rsrc);

  unsigned short* Tx0 = TxAll;
  unsigned short* Tx1 = TxAll + 1ull * N_NODES * 512;
  unsigned short* Tx2 = TxAll + 2ull * N_NODES * 512;
  unsigned short* Tx3 = TxAll + 3ull * N_NODES * 512;
  unsigned short* Tx4 = TxAll + 4ull * N_NODES * 512;

  // Tx1 = prop(Tx0) = -0.05*sum ; Tx_k = 2*prop(Tx_{k-1}) - Tx_{k-2} = -0.10*sum - prev
  prop_kernel<<<2504, 256, 0, stream>>>(Tx0, nullptr, Tx1, rptr, rsrc, perm, -0.05f);
  prop_kernel<<<2504, 256, 0, stream>>>(Tx1, Tx0,     Tx2, rptr, rsrc, perm, -0.10f);
  prop_kernel<<<2504, 256, 0, stream>>>(Tx2, Tx1,     Tx3, rptr, rsrc, perm, -0.10f);
  prop_kernel<<<2504, 256, 0, stream>>>(Tx3, Tx2,     Tx4, rptr, rsrc, perm, -0.10f);

  gemm_kernel<<<320, 256, 0, stream>>>(TxAll, thetabT, bias, (float*)d_out);
}

// Round 15
// 227.028 us; speedup vs baseline: 1.1810x; 1.0199x over previous
//
// Round 15: gemm K-loop -> counted-vmcnt 2-phase pipeline (raw s_barrier +
// s_waitcnt vmcnt(8), never draining to 0 mid-loop). Round-14's __syncthreads
// forced vmcnt(0) every step => 1.2us/step serial latency (48.9us, MfmaUtil 20%).
// Everything else byte-identical to round-14 pass (231.5us).
#include <hip/hip_runtime.h>
#include <hip/hip_bf16.h>
#include <cstdint>
#include <cstddef>

#define N_NODES 10000
#define KNN_K 20
#define NEDGE (N_NODES * KNN_K)
#define NBATCH 157                 // ceil(10000/64)
#define POS4_PAD 10048             // 157*64
#define NCELL 4096                 // 16x16x16 spatial cells, h=0.5
#define NPX 1250                   // nodes per XCD chunk (10000/8)
#define GM_PAIRS 316               // 79 n-tiles x 4 o-tiles

using bf16x8 = __attribute__((ext_vector_type(8))) short;
using f32x4  = __attribute__((ext_vector_type(4))) float;

__device__ __forceinline__ float bf_lo(unsigned int u) {
  union { unsigned int i; float f; } c; c.i = u << 16; return c.f;
}
__device__ __forceinline__ float bf_hi(unsigned int u) {
  union { unsigned int i; float f; } c; c.i = u & 0xFFFF0000u; return c.f;
}
__device__ __forceinline__ unsigned short f2bf(float f) {
  union { float f; unsigned int i; } c; c.f = f;
  unsigned int u = c.i;
  u += 0x7FFFu + ((u >> 16) & 1u);   // RNE
  return (unsigned short)(u >> 16);
}

__device__ __forceinline__ void gll16(const void* g, void* l) {
  __builtin_amdgcn_global_load_lds(
      (const __attribute__((address_space(1))) unsigned int*)g,
      (__attribute__((address_space(3))) unsigned int*)l,
      16, 0, 0);
}

// ---------------- transpose f32 [srows][scols] -> bf16 dst[col][dcol0 + row] ----------------
__global__ __launch_bounds__(256) void transpose_f32_bf16(
    const float* __restrict__ src0, unsigned short* __restrict__ dst,
    int srows, int scols, int dstride, size_t slice_elems, int dcol_per_slice)
{
  __shared__ float lds[64 * 65];
  const int z = blockIdx.z;
  const float* src = src0 + (size_t)z * slice_elems;
  const int dcol0 = z * dcol_per_slice;
  const int c0 = blockIdx.x * 64;
  const int r0 = blockIdx.y * 64;
  const int tid = threadIdx.x;
#pragma unroll
  for (int q = 0; q < 4; ++q) {
    int unit = q * 256 + tid;            // 1024 float4 units
    int rr = unit >> 4;                  // 0..63
    int cu = unit & 15;                  // 0..15
    int r = r0 + rr, c = c0 + cu * 4;
    float4 v = make_float4(0.f, 0.f, 0.f, 0.f);
    if (r < srows && c + 3 < scols) v = *(const float4*)&src[(size_t)r * scols + c];
    lds[rr * 65 + cu * 4 + 0] = v.x;
    lds[rr * 65 + cu * 4 + 1] = v.y;
    lds[rr * 65 + cu * 4 + 2] = v.z;
    lds[rr * 65 + cu * 4 + 3] = v.w;
  }
  __syncthreads();
#pragma unroll
  for (int q = 0; q < 2; ++q) {
    int unit = q * 256 + tid;            // 512 units of 8 bf16
    int cl = unit >> 3;                  // src col within tile (= dst row)
    int ru = unit & 7;
    int c = c0 + cl;
    if (c < scols) {
      unsigned short tmp[8];
#pragma unroll
      for (int j = 0; j < 8; ++j) tmp[j] = f2bf(lds[(ru * 8 + j) * 65 + cl]);
      uint4 o;
      o.x = (unsigned int)tmp[0] | ((unsigned int)tmp[1] << 16);
      o.y = (unsigned int)tmp[2] | ((unsigned int)tmp[3] << 16);
      o.z = (unsigned int)tmp[4] | ((unsigned int)tmp[5] << 16);
      o.w = (unsigned int)tmp[6] | ((unsigned int)tmp[7] << 16);
      *(uint4*)&dst[(size_t)c * dstride + dcol0 + r0 + ru * 8] = o;
    }
  }
}

// ---- pos4: pack (x,y,z,|p|^2); pad w=+INF; zero counts/cursor/nfail; cell hist ----
__global__ __launch_bounds__(256) void pos4_kernel(
    const float* __restrict__ pos, float4* __restrict__ pos4,
    int* __restrict__ counts, int* __restrict__ cursor,
    int* __restrict__ cellid, int* __restrict__ cellcnt,
    int* __restrict__ nfail)
{
  int c = blockIdx.x * 256 + threadIdx.x;      // grid 40 -> 10240 threads
  if (c == 0) *nfail = 0;
  if (c < POS4_PAD) {
    float4 v;
    if (c < N_NODES) {
      float x = pos[c * 3 + 0], y = pos[c * 3 + 1], z = pos[c * 3 + 2];
      v = make_float4(x, y, z, x * x + y * y + z * z);
      int cx = min(15, max(0, (int)floorf((x + 4.0f) * 2.0f)));
      int cy = min(15, max(0, (int)floorf((y + 4.0f) * 2.0f)));
      int cz = min(15, max(0, (int)floorf((z + 4.0f) * 2.0f)));
      int cell = (cx << 8) | (cy << 4) | cz;
      cellid[c] = cell;
      atomicAdd(&cellcnt[cell], 1);
      counts[c] = 0; cursor[c] = 0;
    } else {
      v = make_float4(0.f, 0.f, 0.f, __builtin_inff());   // d -> +INF
    }
    pos4[c] = v;
  }
}

// cell-histogram exclusive scan: 1 block, 16 cells/thread
__global__ __launch_bounds__(256) void cellscan_kernel(
    const int* __restrict__ cellcnt, int* __restrict__ cellptr)
{
  __shared__ int part[256];
  const int tid = threadIdx.x;
  const int base = tid * 16;
  int cv[16];
  int s = 0;
#pragma unroll
  for (int q = 0; q < 4; ++q) {
    int4 v = *(const int4*)&cellcnt[base + q * 4];
    cv[q * 4 + 0] = v.x; cv[q * 4 + 1] = v.y;
    cv[q * 4 + 2] = v.z; cv[q * 4 + 3] = v.w;
    s += v.x + v.y + v.z + v.w;
  }
  part[tid] = s;
  __syncthreads();
  for (int off = 1; off < 256; off <<= 1) {
    int add = (tid >= off) ? part[tid - off] : 0;
    __syncthreads();
    part[tid] += add;
    __syncthreads();
  }
  int run = part[tid] - s;
#pragma unroll
  for (int q = 0; q < 16; ++q) { cellptr[base + q] = run; run += cv[q]; }
  if (tid == 255) cellptr[NCELL] = run;
}

// counting-sort scatter: perm (cell-grouped node ids) + pos4s (sorted coords)
__global__ __launch_bounds__(256) void perm_kernel(
    const int* __restrict__ cellid, const int* __restrict__ cellptr,
    int* __restrict__ cellcur, int* __restrict__ perm,
    const float4* __restrict__ pos4, float4* __restrict__ pos4s)
{
  int c = blockIdx.x * 256 + threadIdx.x;
  if (c < N_NODES) {
    int cell = cellid[c];
    int p = atomicAdd(&cellcur[cell], 1);
    int slot = cellptr[cell] + p;
    perm[slot] = c;
    pos4s[slot] = pos4[c];
  }
}

// identical expression everywhere -> bit-identical distances
__device__ __forceinline__ float knn_dist(float4 pi, float4 s) {
  float dot = fmaf(pi.x, s.x, fmaf(pi.y, s.y, pi.z * s.z));
  return fmaf(-2.0f, dot, pi.w + s.w);
}

__device__ __forceinline__ void insert8(float r[8], float k) {
  // r ascending; r_j = median(k, r_{j-1}, r_j)
  asm("v_med3_f32 %0, %1, %2, %3" : "=v"(r[7]) : "v"(k), "v"(r[6]), "v"(r[7]));
  asm("v_med3_f32 %0, %1, %2, %3" : "=v"(r[6]) : "v"(k), "v"(r[5]), "v"(r[6]));
  asm("v_med3_f32 %0, %1, %2, %3" : "=v"(r[5]) : "v"(k), "v"(r[4]), "v"(r[5]));
  asm("v_med3_f32 %0, %1, %2, %3" : "=v"(r[4]) : "v"(k), "v"(r[3]), "v"(r[4]));
  asm("v_med3_f32 %0, %1, %2, %3" : "=v"(r[3]) : "v"(k), "v"(r[2]), "v"(r[3]));
  asm("v_med3_f32 %0, %1, %2, %3" : "=v"(r[2]) : "v"(k), "v"(r[1]), "v"(r[2]));
  asm("v_med3_f32 %0, %1, %2, %3" : "=v"(r[1]) : "v"(k), "v"(r[0]), "v"(r[1]));
  r[0] = fminf(r[0], k);
}

__device__ __forceinline__ float merge_tau20(float r[8], int lane) {
  const float INF = __builtin_inff();
  float tau = INF;
#pragma unroll
  for (int t = 0; t < KNN_K; ++t) {
    float m = r[0];
    m = fminf(m, __shfl_xor(m, 1));
    m = fminf(m, __shfl_xor(m, 2));
    m = fminf(m, __shfl_xor(m, 4));
    m = fminf(m, __shfl_xor(m, 8));
    m = fminf(m, __shfl_xor(m, 16));
    m = fminf(m, __shfl_xor(m, 32));
    unsigned long long who = __ballot(r[0] == m);
    int srcl = __ffsll(who) - 1;
    if (lane == srcl) {
#pragma unroll
      for (int z = 0; z < 7; ++z) r[z] = r[z + 1];
      r[7] = INF;
    }
    tau = m;
  }
  return tau;   // exact 20th smallest (INF if <20 candidates)
}

__device__ __forceinline__ void emit_hits(
    int i, bool valid, float d, float tau, int cid, int lane, int& cnt,
    int* __restrict__ knn_out)
{
  unsigned long long less = __ballot(valid && d < tau);
  unsigned long long eq   = __ballot(valid && d == tau);
  if (less) {
    if (valid && d < tau) {
      int pos = cnt + (int)__popcll(less & ((1ull << lane) - 1ull));
      if (pos < KNN_K) knn_out[i * KNN_K + pos] = cid;
    }
    cnt += (int)__popcll(less);
  }
  if (eq && cnt < KNN_K) {
    if (valid && d == tau) {
      int pos = cnt + (int)__popcll(eq & ((1ull << lane) - 1ull));
      if (pos < KNN_K) knn_out[i * KNN_K + pos] = cid;
    }
    cnt = min(KNN_K, cnt + (int)__popcll(eq));
  }
}

// ---------------- kNN try: 3^3 grid-pruned exact (round-10 path); else worklist ----------------
__global__ __launch_bounds__(256) void knn_try_kernel(
    const float4* __restrict__ pos4, const float4* __restrict__ pos4s,
    const int* __restrict__ perm, const int* __restrict__ cellptr,
    int* __restrict__ knn_out, int* __restrict__ wl, int* __restrict__ nfail)
{
  const int lane = threadIdx.x & 63, wave = threadIdx.x >> 6;
  const int wid = blockIdx.x * 4 + wave;
  const int i = perm[wid];                         // perm-ordered queries: L2 locality
  const float4 pi = pos4[i];
  const float INF = __builtin_inff();

  const int cx = min(15, max(0, (int)floorf((pi.x + 4.0f) * 2.0f)));
  const int cy = min(15, max(0, (int)floorf((pi.y + 4.0f) * 2.0f)));
  const int cz = min(15, max(0, (int)floorf((pi.z + 4.0f) * 2.0f)));
  const int x0 = max(cx - 1, 0), x1 = min(cx + 1, 15);
  const int y0 = max(cy - 1, 0), y1 = min(cy + 1, 15);
  const int z0 = max(cz - 1, 0), z1 = min(cz + 1, 15);

  float r[8];
#pragma unroll
  for (int q = 0; q < 8; ++q) r[q] = INF;

  // phase A: top-8 over the <=27-cell block (z-contiguous ranges)
  for (int X = x0; X <= x1; ++X)
    for (int Y = y0; Y <= y1; ++Y) {
      const int cb = (X << 8) | (Y << 4);
      const int s0 = cellptr[cb + z0], s1 = cellptr[cb + z1 + 1];
      for (int c0 = s0; c0 < s1; c0 += 64) {
        const int slot = c0 + lane;
        const int idx = min(slot, s1 - 1);
        const float4 s = pos4s[idx];
        const int nid = perm[idx];
        float d = knn_dist(pi, s);
        float k = (slot < s1 && nid != i) ? d : INF;
        insert8(r, k);
      }
    }
  float tau = merge_tau20(r, lane);

  // exactness margin: distance from query to scanned-region boundary
  float mx = INF, my = INF, mz = INF;
  if (x0 > 0)  mx = pi.x - (x0 * 0.5f - 4.0f);
  if (x1 < 15) mx = fminf(mx, ((x1 + 1) * 0.5f - 4.0f) - pi.x);
  if (y0 > 0)  my = pi.y - (y0 * 0.5f - 4.0f);
  if (y1 < 15) my = fminf(my, ((y1 + 1) * 0.5f - 4.0f) - pi.y);
  if (z0 > 0)  mz = pi.z - (z0 * 0.5f - 4.0f);
  if (z1 < 15) mz = fminf(mz, ((z1 + 1) * 0.5f - 4.0f) - pi.z);
  const float marg = fminf(mx, fminf(my, mz));

  if (tau < marg * marg) {
    // accepted: ball(sqrt(tau)) inside scanned region -> exact neighbor set
    int cnt = 0;
    for (int X = x0; X <= x1; ++X)
      for (int Y = y0; Y <= y1; ++Y) {
        const int cb = (X << 8) | (Y << 4);
        const int s0 = cellptr[cb + z0], s1 = cellptr[cb + z1 + 1];
        for (int c0 = s0; c0 < s1; c0 += 64) {
          const int slot = c0 + lane;
          const int idx = min(slot, s1 - 1);
          const float4 s = pos4s[idx];
          const int nid = perm[idx];
          float d = knn_dist(pi, s);
          bool valid = (slot < s1) && (nid != i);
          emit_hits(i, valid, d, tau, nid, lane, cnt, knn_out);
        }
      }
    return;
  }

  // failed: defer to knn_full (round-6 exact full scan)
  if (lane == 0) {
    int slot = atomicAdd(nfail, 1);
    wl[slot] = i;
  }
}

// ---------------- kNN full scan, block-per-query: 4 waves split the batches ----------------
__global__ __launch_bounds__(256) void knn_full_kernel(
    const float4* __restrict__ pos4, const int* __restrict__ wl,
    const int* __restrict__ nfail, int* __restrict__ knn_out)
{
  __shared__ float wmin[4];
  __shared__ int lcnt, eqcnt;
  __shared__ int eqbuf[64];
  const int tid = threadIdx.x;
  const int lane = tid & 63, wave = tid >> 6;
  const float INF = __builtin_inff();
  const int nf = *nfail;

  for (int w = blockIdx.x; w < nf; w += 2500) {
    const int i = wl[w];
    const float4 pi = pos4[i];

    // phase 1: wave `wave` scans batches b ≡ wave (mod 4); per-lane top-8
    float r[8];
#pragma unroll
    for (int q = 0; q < 8; ++q) r[q] = INF;
    for (int b = wave; b < NBATCH; b += 4) {
      const int cid = b * 64 + lane;
      const float4 s = pos4[cid];
      float d = knn_dist(pi, s);                  // pad rows: +INF
      float k = (cid == i) ? INF : d;
      insert8(r, k);
    }

    // block-level exact tau: 20 extract-min rounds across 4 waves
    float tau = INF;
#pragma unroll
    for (int t = 0; t < KNN_K; ++t) {
      float m = r[0];
      m = fminf(m, __shfl_xor(m, 1));
      m = fminf(m, __shfl_xor(m, 2));
      m = fminf(m, __shfl_xor(m, 4));
      m = fminf(m, __shfl_xor(m, 8));
      m = fminf(m, __shfl_xor(m, 16));
      m = fminf(m, __shfl_xor(m, 32));
      if (lane == 0) wmin[wave] = m;
      __syncthreads();
      float m0 = wmin[0], m1 = wmin[1], m2 = wmin[2], m3 = wmin[3];
      float gm = fminf(fminf(m0, m1), fminf(m2, m3));
      int wsel = (m0 == gm) ? 0 : ((m1 == gm) ? 1 : ((m2 == gm) ? 2 : 3));
      __syncthreads();                             // wmin consumed; safe for next round
      if (wave == wsel) {
        unsigned long long who = __ballot(r[0] == gm);
        int srcl = __ffsll(who) - 1;               // non-empty: wsel's min == gm
        if (lane == srcl) {
#pragma unroll
          for (int z = 0; z < 7; ++z) r[z] = r[z + 1];
          r[7] = INF;
        }
      }
      tau = gm;
    }

    // phase 2: emit. d<tau -> atomic unique slots (set-exact, order-free);
    // d==tau ties -> collect, sort by id, lowest-first fill to 20.
    if (tid == 0) { lcnt = 0; eqcnt = 0; }
    __syncthreads();
    for (int b = wave; b < NBATCH; b += 4) {
      const int cid = b * 64 + lane;
      const float4 s = pos4[cid];
      float d = knn_dist(pi, s);
      bool valid = (cid != i);                     // pad rows: d=INF, never accepted
      if (valid && d < tau) {
        int slot = atomicAdd(&lcnt, 1);
        if (slot < KNN_K) knn_out[i * KNN_K + slot] = cid;
      }
      if (valid && d == tau) {
        int e = atomicAdd(&eqcnt, 1);
        if (e < 64) eqbuf[e] = cid;
      }
    }
    __syncthreads();
    if (tid == 0) {
      int base = lcnt;                             // <= 19 (tau = 20th smallest)
      int ne = min(eqcnt, 64);
      for (int a = 1; a < ne; ++a) {               // tiny insertion sort by id
        int v = eqbuf[a];
        int b2 = a - 1;
        while (b2 >= 0 && eqbuf[b2] > v) { eqbuf[b2 + 1] = eqbuf[b2]; --b2; }
        eqbuf[b2 + 1] = v;
      }
      for (int q = 0; q < ne && base + q < KNN_K; ++q)
        knn_out[i * KNN_K + base + q] = eqbuf[q];
    }
    __syncthreads();                               // lcnt/eqcnt reused next iter
  }
}

// ---------------- reverse-CSR build ----------------
__global__ __launch_bounds__(256) void count_kernel(
    const int* __restrict__ knn, int* __restrict__ counts)
{
  int e = blockIdx.x * 256 + threadIdx.x;
  if (e < NEDGE) atomicAdd(&counts[knn[e]], 1);
}

// node-degree exclusive scan (int4 loads; 250 threads x 40 exact)
__global__ __launch_bounds__(256) void scan_kernel(
    const int* __restrict__ counts, int* __restrict__ rptr)
{
  __shared__ int part[256];
  const int tid = threadIdx.x;
  const int base = tid * 40;                       // 250*40 = 10000 exact
  int s = 0;
  int cv[40];
  if (tid < 250) {
#pragma unroll
    for (int q = 0; q < 10; ++q) {
      int4 v = *(const int4*)&counts[base + q * 4];
      cv[q * 4 + 0] = v.x; cv[q * 4 + 1] = v.y;
      cv[q * 4 + 2] = v.z; cv[q * 4 + 3] = v.w;
      s += v.x + v.y + v.z + v.w;
    }
  }
  part[tid] = s;
  __syncthreads();
  for (int off = 1; off < 256; off <<= 1) {
    int add = (tid >= off) ? part[tid - off] : 0;
    __syncthreads();
    part[tid] += add;
    __syncthreads();
  }
  int run = part[tid] - s;                         // exclusive offset
  if (tid < 250) {
#pragma unroll
    for (int q = 0; q < 40; ++q) { rptr[base + q] = run; run += cv[q]; }
  }
  if (tid == 255) rptr[N_NODES] = run;
}

__global__ __launch_bounds__(256) void fill_kernel(
    const int* __restrict__ knn, const int* __restrict__ rptr,
    int* __restrict__ cursor, int* __restrict__ rsrc)
{
  int e = blockIdx.x * 256 + threadIdx.x;
  if (e < NEDGE) {
    int j = knn[e];
    int i = e / KNN_K;
    int p = atomicAdd(&cursor[j], 1);
    rsrc[rptr[j] + p] = i;
  }
}

// sort each reverse-adjacency list ascending (bitonic-64 per wave)
__global__ __launch_bounds__(256) void sort_kernel(
    const int* __restrict__ rptr, int* __restrict__ rsrc)
{
  const int lane = threadIdx.x & 63, wave = threadIdx.x >> 6;
  const int j = blockIdx.x * 4 + wave;
  const int s0 = rptr[j], s1 = rptr[j + 1], deg = s1 - s0;
  if (deg <= 64) {
    int v = (lane < deg) ? rsrc[s0 + lane] : 0x7FFFFFFF;
#pragma unroll
    for (int k = 2; k <= 64; k <<= 1) {
#pragma unroll
      for (int m = k >> 1; m > 0; m >>= 1) {
        int other = __shfl_xor(v, m);
        bool up = ((lane & k) == 0);
        bool lower = ((lane & m) == 0);
        v = (up == lower) ? min(v, other) : max(v, other);
      }
    }
    if (lane < deg) rsrc[s0 + lane] = v;
  } else if (lane == 0) {
    for (int a = s0 + 1; a < s1; ++a) {
      int v = rsrc[a];
      int b = a - 1;
      while (b >= s0 && rsrc[b] > v) { rsrc[b + 1] = rsrc[b]; --b; }
      rsrc[b + 1] = v;
    }
  }
}

// ---------------- prop: out[j] = scale2 * sum_{i in rev(j)} t[i] - prev[j] ----------------
// XCD-chunked spatial schedule (perm is cell-sorted -> L2-local gathers)
__global__ __launch_bounds__(256) void prop_kernel(
    const unsigned short* __restrict__ tin, const unsigned short* __restrict__ tprev,
    unsigned short* __restrict__ tout, const int* __restrict__ rptr,
    const int* __restrict__ rsrc, const int* __restrict__ perm, float scale2)
{
  const int wave = threadIdx.x >> 6, lane = threadIdx.x & 63;
  const int b = blockIdx.x;                        // grid 2504
  const int xcd = b & 7, qb = b >> 3;
  const int local = qb * 4 + wave;
  if (local >= NPX) return;                        // no barriers below: safe
  const int j = perm[xcd * NPX + local];
  const int s0 = rptr[j], s1 = rptr[j + 1];
  const size_t coff = (size_t)lane * 8;

  float a0[8], a1[8], a2[8], a3[8];
#pragma unroll
  for (int q = 0; q < 8; ++q) { a0[q] = 0.f; a1[q] = 0.f; a2[q] = 0.f; a3[q] = 0.f; }

  for (int base = s0; base < s1; base += 64) {
    const int clen = min(64, s1 - base);
    int myidx = (base + lane < s1) ? rsrc[base + lane] : 0;
    int t = 0;
    for (; t + 4 <= clen; t += 4) {
      int i0 = __shfl(myidx, t);
      int i1 = __shfl(myidx, t + 1);
      int i2 = __shfl(myidx, t + 2);
      int i3 = __shfl(myidx, t + 3);
      uint4 v0 = *(const uint4*)&tin[(size_t)i0 * 512 + coff];
      uint4 v1 = *(const uint4*)&tin[(size_t)i1 * 512 + coff];
      uint4 v2 = *(const uint4*)&tin[(size_t)i2 * 512 + coff];
      uint4 v3 = *(const uint4*)&tin[(size_t)i3 * 512 + coff];
      a0[0] += bf_lo(v0.x); a0[1] += bf_hi(v0.x); a0[2] += bf_lo(v0.y); a0[3] += bf_hi(v0.y);
      a0[4] += bf_lo(v0.z); a0[5] += bf_hi(v0.z); a0[6] += bf_lo(v0.w); a0[7] += bf_hi(v0.w);
      a1[0] += bf_lo(v1.x); a1[1] += bf_hi(v1.x); a1[2] += bf_lo(v1.y); a1[3] += bf_hi(v1.y);
      a1[4] += bf_lo(v1.z); a1[5] += bf_hi(v1.z); a1[6] += bf_lo(v1.w); a1[7] += bf_hi(v1.w);
      a2[0] += bf_lo(v2.x); a2[1] += bf_hi(v2.x); a2[2] += bf_lo(v2.y); a2[3] += bf_hi(v2.y);
      a2[4] += bf_lo(v2.z); a2[5] += bf_hi(v2.z); a2[6] += bf_lo(v2.w); a2[7] += bf_hi(v2.w);
      a3[0] += bf_lo(v3.x); a3[1] += bf_hi(v3.x); a3[2] += bf_lo(v3.y); a3[3] += bf_hi(v3.y);
      a3[4] += bf_lo(v3.z); a3[5] += bf_hi(v3.z); a3[6] += bf_lo(v3.w); a3[7] += bf_hi(v3.w);
    }
    for (; t < clen; ++t) {
      int i0 = __shfl(myidx, t);
      uint4 v0 = *(const uint4*)&tin[(size_t)i0 * 512 + coff];
      a0[0] += bf_lo(v0.x); a0[1] += bf_hi(v0.x); a0[2] += bf_lo(v0.y); a0[3] += bf_hi(v0.y);
      a0[4] += bf_lo(v0.z); a0[5] += bf_hi(v0.z); a0[6] += bf_lo(v0.w); a0[7] += bf_hi(v0.w);
    }
  }

  float pv[8] = {0.f, 0.f, 0.f, 0.f, 0.f, 0.f, 0.f, 0.f};
  if (tprev != nullptr) {
    uint4 p = *(const uint4*)&tprev[(size_t)j * 512 + coff];
    pv[0] = bf_lo(p.x); pv[1] = bf_hi(p.x);
    pv[2] = bf_lo(p.y); pv[3] = bf_hi(p.y);
    pv[4] = bf_lo(p.z); pv[5] = bf_hi(p.z);
    pv[6] = bf_lo(p.w); pv[7] = bf_hi(p.w);
  }
  unsigned short o16[8];
#pragma unroll
  for (int q = 0; q < 8; ++q) {
    float acc = (a0[q] + a1[q]) + (a2[q] + a3[q]);   // fixed tree, deterministic
    o16[q] = f2bf(scale2 * acc - pv[q]);
  }
  uint4 o;
  o.x = (unsigned int)o16[0] | ((unsigned int)o16[1] << 16);
  o.y = (unsigned int)o16[2] | ((unsigned int)o16[3] << 16);
  o.z = (unsigned int)o16[4] | ((unsigned int)o16[5] << 16);
  o.w = (unsigned int)o16[6] | ((unsigned int)o16[7] << 16);
  *(uint4*)&tout[(size_t)j * 512 + coff] = o;
}

// ---------------- GEMM: C[o][n] = sum_kc A[n][kc] * B[kc][o] + bias[o] ----------------
// Double-buffered LDS + counted-vmcnt 2-phase pipeline (raw s_barrier, vmcnt(8)
// mid-loop — tile kt+1 loads stay in flight across barriers). T2 XOR swizzle.
__global__ __launch_bounds__(256) void gemm_kernel(
    const unsigned short* __restrict__ A,
    const unsigned short* __restrict__ Bt,
    const float* __restrict__ bias,
    float* __restrict__ C)
{
  __shared__ __align__(16) char smem[65536];          // 2 x (As 16KB + Bs 16KB)
  float* eps = (float*)smem;                          // epilogue [64 o][132] f32

  const int tid = threadIdx.x;
  const int wave = tid >> 6, lane = tid & 63;
  const int l15 = lane & 15, hi = lane >> 4;
  const int wr = wave >> 1, wc = wave & 1;

  // bijective XCD-chunked mapping of 316 (n,o) pairs, n-major
  const int bid = blockIdx.x;                         // 0..319
  const int xcd = bid & 7, local = bid >> 3;
  const int qd = GM_PAIRS >> 3, rem = GM_PAIRS & 7;   // 39, 4
  const int cnt = (xcd < rem) ? qd + 1 : qd;
  if (local >= cnt) return;                           // whole block exits: safe
  const int start = (xcd < rem) ? xcd * (qd + 1) : rem * (qd + 1) + (xcd - rem) * qd;
  const int pair = start + local;
  const int n0 = (pair >> 2) * 128;
  const int o0 = (pair & 3) * 128;

  f32x4 acc[4][4];
#pragma unroll
  for (int a = 0; a < 4; ++a)
#pragma unroll
    for (int b = 0; b < 4; ++b) acc[a][b] = (f32x4){0.f, 0.f, 0.f, 0.f};

  // stage K-tile kt into buffer sel. LDS dest linear (slot = unit idx);
  // global 16B-unit column pre-swizzled: u_g = u ^ (r&7).
  auto stage = [&](int kt, int sel) {
    const int k0 = kt * 64;
    const int ko = k0 >> 9;
    const int c0 = k0 & 511;
    const unsigned short* Ab = A + (size_t)ko * ((size_t)N_NODES * 512);
    unsigned short* As = (unsigned short*)(smem + sel * 32768);
    unsigned short* Bs = As + 128 * 64;
#pragma unroll
    for (int q = 0; q < 4; ++q) {
      int idx = (wave * 4 + q) * 64 + lane;           // 16B unit id, 0..1023
      int r = idx >> 3, u = idx & 7;
      int ug = u ^ (r & 7);
      gll16(Ab + (size_t)(n0 + r) * 512 + c0 + ug * 8, As + (size_t)(wave * 4 + q) * 512);
    }
#pragma unroll
    for (int q = 0; q < 4; ++q) {
      int idx = (wave * 4 + q) * 64 + lane;
      int r = idx >> 3, u = idx & 7;
      int ug = u ^ (r & 7);
      gll16(Bt + (size_t)(o0 + r) * 2560 + k0 + ug * 8, Bs + (size_t)(wave * 4 + q) * 512);
    }
  };

  stage(0, 0);
  asm volatile("s_waitcnt vmcnt(0)" ::: "memory");     // tile 0 resident
  __builtin_amdgcn_s_barrier();

  for (int kt = 0; kt < 40; ++kt) {
    const int cur = kt & 1;
    if (kt + 1 < 40) {
      stage(kt + 1, cur ^ 1);                          // 8 loads join flight
      asm volatile("s_waitcnt vmcnt(8)" ::: "memory"); // my tile-kt 8 complete
    } else {
      asm volatile("s_waitcnt vmcnt(0)" ::: "memory"); // last tile: drain
    }
    __builtin_amdgcn_s_barrier();                      // all waves: tile kt in LDS
    __builtin_amdgcn_sched_barrier(0);                 // pin ds_reads below
    unsigned short* As = (unsigned short*)(smem + cur * 32768);
    unsigned short* Bs = As + 128 * 64;
#pragma unroll
    for (int kk = 0; kk < 2; ++kk) {
      bf16x8 af[4], bfr[4];
#pragma unroll
      for (int mi = 0; mi < 4; ++mi) {
        int row = wr * 64 + mi * 16 + l15;
        int up = (kk * 4 + hi) ^ (row & 7);            // read-side XOR
        af[mi] = *(const bf16x8*)(As + row * 64 + up * 8);
      }
#pragma unroll
      for (int ni = 0; ni < 4; ++ni) {
        int row = wc * 64 + ni * 16 + l15;
        int up = (kk * 4 + hi) ^ (row & 7);
        bfr[ni] = *(const bf16x8*)(Bs + row * 64 + up * 8);
      }
#pragma unroll
      for (int mi = 0; mi < 4; ++mi)
#pragma unroll
        for (int ni = 0; ni < 4; ++ni)
          acc[mi][ni] = __builtin_amdgcn_mfma_f32_16x16x32_bf16(af[mi], bfr[ni], acc[mi][ni], 0, 0, 0);
    }
    // reads of buf cur done (lgkm drained by MFMA deps) -> next stage may
    // overwrite it only after every wave passes this barrier.
    __builtin_amdgcn_s_barrier();
  }

  // epilogue: LDS-transposed coalesced store of C[o][n] + bias
#pragma unroll
  for (int h = 0; h < 2; ++h) {
    __syncthreads();
    if (wc == h) {
#pragma unroll
      for (int mi = 0; mi < 4; ++mi)
#pragma unroll
        for (int ni = 0; ni < 4; ++ni) {
          int o_l = ni * 16 + l15;                   // 0..63 within half
          int nb = wr * 64 + mi * 16 + hi * 4;       // 0..124, x4 aligned
          *(f32x4*)&eps[o_l * 132 + nb] = acc[mi][ni];
        }
    }
    __syncthreads();
#pragma unroll
    for (int q = 0; q < 8; ++q) {
      int unit = q * 256 + tid;                      // 2048 float4 units
      int o_l = unit >> 5, nu = unit & 31;
      int n = n0 + nu * 4;
      if (n < N_NODES) {
        int o = o0 + h * 64 + o_l;
        f32x4 v = *(const f32x4*)&eps[o_l * 132 + nu * 4];
        float bo = bias[o];
        v = v + bo;
        *(f32x4*)&C[(size_t)o * N_NODES + n] = v;
      }
    }
  }
}

extern "C" void kernel_launch(void* const* d_in, const int* in_sizes, int n_in,
                              void* d_out, int out_size, void* d_ws, size_t ws_size,
                              hipStream_t stream)
{
  const float* x        = (const float*)d_in[0];   // [512][10000]
  const float* position = (const float*)d_in[1];   // [10000][3]
  const float* theta    = (const float*)d_in[2];   // [5][512][512]
  const float* bias     = (const float*)d_in[3];   // [512]

  char* ws = (char*)d_ws;
  size_t off = 0;
  auto alloc = [&](size_t bytes) -> void* {
    void* p = ws + off;
    off = (off + bytes + 255) & ~(size_t)255;
    return p;
  };
  unsigned short* TxAll   = (unsigned short*)alloc(5ull * N_NODES * 512 * 2 + 131072); // +128-row pad
  unsigned short* thetabT = (unsigned short*)alloc(512ull * 2560 * 2);
  float4* pos4  = (float4*)alloc((size_t)POS4_PAD * 16);
  float4* pos4s = (float4*)alloc((size_t)N_NODES * 16);
  int* knn    = (int*)alloc((size_t)NEDGE * 4);
  int* rptr   = (int*)alloc((size_t)(N_NODES + 1) * 4);
  int* counts = (int*)alloc((size_t)N_NODES * 4);
  int* cursor = (int*)alloc((size_t)N_NODES * 4);
  int* rsrc   = (int*)alloc((size_t)NEDGE * 4);
  int* cellcnt = (int*)alloc((size_t)NCELL * 4);   // contiguous with cellcur:
  int* cellcur = (int*)alloc((size_t)NCELL * 4);   // one memset covers both
  int* cellptr = (int*)alloc((size_t)(NCELL + 1) * 4);
  int* cellid  = (int*)alloc((size_t)N_NODES * 4);
  int* perm    = (int*)alloc((size_t)N_NODES * 4);
  int* wl      = (int*)alloc((size_t)N_NODES * 4);
  int* nfail   = (int*)alloc(256);
  if (ws_size < off) return;   // insufficient scratch

  // theta [5][512][512] -> thetabT [o=512][kc=2560]
  transpose_f32_bf16<<<dim3(8, 8, 5), 256, 0, stream>>>(
      theta, thetabT, 512, 512, 2560, (size_t)512 * 512, 512);
  // x [512][10000] -> Tx0 [10000][512]
  transpose_f32_bf16<<<dim3(157, 8, 1), 256, 0, stream>>>(
      x, TxAll, 512, N_NODES, 512, 0, 0);

  hipMemsetAsync(cellcnt, 0, (size_t)((char*)cellptr - (char*)cellcnt), stream);
  pos4_kernel<<<40, 256, 0, stream>>>(position, pos4, counts, cursor, cellid, cellcnt, nfail);
  cellscan_kernel<<<1, 256, 0, stream>>>(cellcnt, cellptr);
  perm_kernel<<<40, 256, 0, stream>>>(cellid, cellptr, cellcur, perm, pos4, pos4s);

  knn_try_kernel<<<2500, 256, 0, stream>>>(pos4, pos4s, perm, cellptr, knn, wl, nfail);
  knn_full_kernel<<<2500, 256, 0, stream>>>(pos4, wl, nfail, knn);

  count_kernel<<<(NEDGE + 255) / 256, 256, 0, stream>>>(knn, counts);
  scan_kernel<<<1, 256, 0, stream>>>(counts, rptr);
  fill_kernel<<<(NEDGE + 255) / 256, 256, 0, stream>>>(knn, rptr, cursor, rsrc);
  sort_kernel<<<2500, 256, 0, stream>>>(rptr, rsrc);

  unsigned short* Tx0 = TxAll;
  unsigned short* Tx1 = TxAll + 1ull * N_NODES * 512;
  unsigned short* Tx2 = TxAll + 2ull * N_NODES * 512;
  unsigned short* Tx3 = TxAll + 3ull * N_NODES * 512;
  unsigned short* Tx4 = TxAll + 4ull * N_NODES * 512;

  // Tx1 = prop(Tx0) = -0.05*sum ; Tx_k = 2*prop(Tx_{k-1}) - Tx_{k-2} = -0.10*sum - prev
  prop_kernel<<<2504, 256, 0, stream>>>(Tx0, nullptr, Tx1, rptr, rsrc, perm, -0.05f);
  prop_kernel<<<2504, 256, 0, stream>>>(Tx1, Tx0,     Tx2, rptr, rsrc, perm, -0.10f);
  prop_kernel<<<2504, 256, 0, stream>>>(Tx2, Tx1,     Tx3, rptr, rsrc, perm, -0.10f);
  prop_kernel<<<2504, 256, 0, stream>>>(Tx3, Tx2,     Tx4, rptr, rsrc, perm, -0.10f);

  gemm_kernel<<<320, 256, 0, stream>>>(TxAll, thetabT, bias, (float*)d_out);
}

// Round 16
// 224.854 us; speedup vs baseline: 1.1925x; 1.0097x over previous
//
// Round 16: gemm tile 128x128 -> 64x128 (grid 316 -> 628 blocks): round-15's
// counters showed the GRID was the limit (9% occupancy, 1 block/CU, nothing to
// overlap the 1-deep prefetch with). 48KB dbuf LDS -> ~2.5 blocks/CU TLP.
// Same T2 swizzle + counted-vmcnt(6) pipeline. Rest identical to round-15 (227us).
#include <hip/hip_runtime.h>
#include <hip/hip_bf16.h>
#include <cstdint>
#include <cstddef>

#define N_NODES 10000
#define KNN_K 20
#define NEDGE (N_NODES * KNN_K)
#define NBATCH 157                 // ceil(10000/64)
#define POS4_PAD 10048             // 157*64
#define NCELL 4096                 // 16x16x16 spatial cells, h=0.5
#define NPX 1250                   // nodes per XCD chunk (10000/8)
#define GM_PAIRS 628               // 157 n-tiles (64) x 4 o-tiles (128)

using bf16x8 = __attribute__((ext_vector_type(8))) short;
using f32x4  = __attribute__((ext_vector_type(4))) float;

__device__ __forceinline__ float bf_lo(unsigned int u) {
  union { unsigned int i; float f; } c; c.i = u << 16; return c.f;
}
__device__ __forceinline__ float bf_hi(unsigned int u) {
  union { unsigned int i; float f; } c; c.i = u & 0xFFFF0000u; return c.f;
}
__device__ __forceinline__ unsigned short f2bf(float f) {
  union { float f; unsigned int i; } c; c.f = f;
  unsigned int u = c.i;
  u += 0x7FFFu + ((u >> 16) & 1u);   // RNE
  return (unsigned short)(u >> 16);
}

__device__ __forceinline__ void gll16(const void* g, void* l) {
  __builtin_amdgcn_global_load_lds(
      (const __attribute__((address_space(1))) unsigned int*)g,
      (__attribute__((address_space(3))) unsigned int*)l,
      16, 0, 0);
}

// ---------------- transpose f32 [srows][scols] -> bf16 dst[col][dcol0 + row] ----------------
__global__ __launch_bounds__(256) void transpose_f32_bf16(
    const float* __restrict__ src0, unsigned short* __restrict__ dst,
    int srows, int scols, int dstride, size_t slice_elems, int dcol_per_slice)
{
  __shared__ float lds[64 * 65];
  const int z = blockIdx.z;
  const float* src = src0 + (size_t)z * slice_elems;
  const int dcol0 = z * dcol_per_slice;
  const int c0 = blockIdx.x * 64;
  const int r0 = blockIdx.y * 64;
  const int tid = threadIdx.x;
#pragma unroll
  for (int q = 0; q < 4; ++q) {
    int unit = q * 256 + tid;            // 1024 float4 units
    int rr = unit >> 4;                  // 0..63
    int cu = unit & 15;                  // 0..15
    int r = r0 + rr, c = c0 + cu * 4;
    float4 v = make_float4(0.f, 0.f, 0.f, 0.f);
    if (r < srows && c + 3 < scols) v = *(const float4*)&src[(size_t)r * scols + c];
    lds[rr * 65 + cu * 4 + 0] = v.x;
    lds[rr * 65 + cu * 4 + 1] = v.y;
    lds[rr * 65 + cu * 4 + 2] = v.z;
    lds[rr * 65 + cu * 4 + 3] = v.w;
  }
  __syncthreads();
#pragma unroll
  for (int q = 0; q < 2; ++q) {
    int unit = q * 256 + tid;            // 512 units of 8 bf16
    int cl = unit >> 3;                  // src col within tile (= dst row)
    int ru = unit & 7;
    int c = c0 + cl;
    if (c < scols) {
      unsigned short tmp[8];
#pragma unroll
      for (int j = 0; j < 8; ++j) tmp[j] = f2bf(lds[(ru * 8 + j) * 65 + cl]);
      uint4 o;
      o.x = (unsigned int)tmp[0] | ((unsigned int)tmp[1] << 16);
      o.y = (unsigned int)tmp[2] | ((unsigned int)tmp[3] << 16);
      o.z = (unsigned int)tmp[4] | ((unsigned int)tmp[5] << 16);
      o.w = (unsigned int)tmp[6] | ((unsigned int)tmp[7] << 16);
      *(uint4*)&dst[(size_t)c * dstride + dcol0 + r0 + ru * 8] = o;
    }
  }
}

// ---- pos4: pack (x,y,z,|p|^2); pad w=+INF; zero counts/cursor/nfail; cell hist ----
__global__ __launch_bounds__(256) void pos4_kernel(
    const float* __restrict__ pos, float4* __restrict__ pos4,
    int* __restrict__ counts, int* __restrict__ cursor,
    int* __restrict__ cellid, int* __restrict__ cellcnt,
    int* __restrict__ nfail)
{
  int c = blockIdx.x * 256 + threadIdx.x;      // grid 40 -> 10240 threads
  if (c == 0) *nfail = 0;
  if (c < POS4_PAD) {
    float4 v;
    if (c < N_NODES) {
      float x = pos[c * 3 + 0], y = pos[c * 3 + 1], z = pos[c * 3 + 2];
      v = make_float4(x, y, z, x * x + y * y + z * z);
      int cx = min(15, max(0, (int)floorf((x + 4.0f) * 2.0f)));
      int cy = min(15, max(0, (int)floorf((y + 4.0f) * 2.0f)));
      int cz = min(15, max(0, (int)floorf((z + 4.0f) * 2.0f)));
      int cell = (cx << 8) | (cy << 4) | cz;
      cellid[c] = cell;
      atomicAdd(&cellcnt[cell], 1);
      counts[c] = 0; cursor[c] = 0;
    } else {
      v = make_float4(0.f, 0.f, 0.f, __builtin_inff());   // d -> +INF
    }
    pos4[c] = v;
  }
}

// cell-histogram exclusive scan: 1 block, 16 cells/thread
__global__ __launch_bounds__(256) void cellscan_kernel(
    const int* __restrict__ cellcnt, int* __restrict__ cellptr)
{
  __shared__ int part[256];
  const int tid = threadIdx.x;
  const int base = tid * 16;
  int cv[16];
  int s = 0;
#pragma unroll
  for (int q = 0; q < 4; ++q) {
    int4 v = *(const int4*)&cellcnt[base + q * 4];
    cv[q * 4 + 0] = v.x; cv[q * 4 + 1] = v.y;
    cv[q * 4 + 2] = v.z; cv[q * 4 + 3] = v.w;
    s += v.x + v.y + v.z + v.w;
  }
  part[tid] = s;
  __syncthreads();
  for (int off = 1; off < 256; off <<= 1) {
    int add = (tid >= off) ? part[tid - off] : 0;
    __syncthreads();
    part[tid] += add;
    __syncthreads();
  }
  int run = part[tid] - s;
#pragma unroll
  for (int q = 0; q < 16; ++q) { cellptr[base + q] = run; run += cv[q]; }
  if (tid == 255) cellptr[NCELL] = run;
}

// counting-sort scatter: perm (cell-grouped node ids) + pos4s (sorted coords)
__global__ __launch_bounds__(256) void perm_kernel(
    const int* __restrict__ cellid, const int* __restrict__ cellptr,
    int* __restrict__ cellcur, int* __restrict__ perm,
    const float4* __restrict__ pos4, float4* __restrict__ pos4s)
{
  int c = blockIdx.x * 256 + threadIdx.x;
  if (c < N_NODES) {
    int cell = cellid[c];
    int p = atomicAdd(&cellcur[cell], 1);
    int slot = cellptr[cell] + p;
    perm[slot] = c;
    pos4s[slot] = pos4[c];
  }
}

// identical expression everywhere -> bit-identical distances
__device__ __forceinline__ float knn_dist(float4 pi, float4 s) {
  float dot = fmaf(pi.x, s.x, fmaf(pi.y, s.y, pi.z * s.z));
  return fmaf(-2.0f, dot, pi.w + s.w);
}

__device__ __forceinline__ void insert8(float r[8], float k) {
  // r ascending; r_j = median(k, r_{j-1}, r_j)
  asm("v_med3_f32 %0, %1, %2, %3" : "=v"(r[7]) : "v"(k), "v"(r[6]), "v"(r[7]));
  asm("v_med3_f32 %0, %1, %2, %3" : "=v"(r[6]) : "v"(k), "v"(r[5]), "v"(r[6]));
  asm("v_med3_f32 %0, %1, %2, %3" : "=v"(r[5]) : "v"(k), "v"(r[4]), "v"(r[5]));
  asm("v_med3_f32 %0, %1, %2, %3" : "=v"(r[4]) : "v"(k), "v"(r[3]), "v"(r[4]));
  asm("v_med3_f32 %0, %1, %2, %3" : "=v"(r[3]) : "v"(k), "v"(r[2]), "v"(r[3]));
  asm("v_med3_f32 %0, %1, %2, %3" : "=v"(r[2]) : "v"(k), "v"(r[1]), "v"(r[2]));
  asm("v_med3_f32 %0, %1, %2, %3" : "=v"(r[1]) : "v"(k), "v"(r[0]), "v"(r[1]));
  r[0] = fminf(r[0], k);
}

__device__ __forceinline__ float merge_tau20(float r[8], int lane) {
  const float INF = __builtin_inff();
  float tau = INF;
#pragma unroll
  for (int t = 0; t < KNN_K; ++t) {
    float m = r[0];
    m = fminf(m, __shfl_xor(m, 1));
    m = fminf(m, __shfl_xor(m, 2));
    m = fminf(m, __shfl_xor(m, 4));
    m = fminf(m, __shfl_xor(m, 8));
    m = fminf(m, __shfl_xor(m, 16));
    m = fminf(m, __shfl_xor(m, 32));
    unsigned long long who = __ballot(r[0] == m);
    int srcl = __ffsll(who) - 1;
    if (lane == srcl) {
#pragma unroll
      for (int z = 0; z < 7; ++z) r[z] = r[z + 1];
      r[7] = INF;
    }
    tau = m;
  }
  return tau;   // exact 20th smallest (INF if <20 candidates)
}

__device__ __forceinline__ void emit_hits(
    int i, bool valid, float d, float tau, int cid, int lane, int& cnt,
    int* __restrict__ knn_out)
{
  unsigned long long less = __ballot(valid && d < tau);
  unsigned long long eq   = __ballot(valid && d == tau);
  if (less) {
    if (valid && d < tau) {
      int pos = cnt + (int)__popcll(less & ((1ull << lane) - 1ull));
      if (pos < KNN_K) knn_out[i * KNN_K + pos] = cid;
    }
    cnt += (int)__popcll(less);
  }
  if (eq && cnt < KNN_K) {
    if (valid && d == tau) {
      int pos = cnt + (int)__popcll(eq & ((1ull << lane) - 1ull));
      if (pos < KNN_K) knn_out[i * KNN_K + pos] = cid;
    }
    cnt = min(KNN_K, cnt + (int)__popcll(eq));
  }
}

// ---------------- kNN try: 3^3 grid-pruned exact (round-10 path); else worklist ----------------
__global__ __launch_bounds__(256) void knn_try_kernel(
    const float4* __restrict__ pos4, const float4* __restrict__ pos4s,
    const int* __restrict__ perm, const int* __restrict__ cellptr,
    int* __restrict__ knn_out, int* __restrict__ wl, int* __restrict__ nfail)
{
  const int lane = threadIdx.x & 63, wave = threadIdx.x >> 6;
  const int wid = blockIdx.x * 4 + wave;
  const int i = perm[wid];                         // perm-ordered queries: L2 locality
  const float4 pi = pos4[i];
  const float INF = __builtin_inff();

  const int cx = min(15, max(0, (int)floorf((pi.x + 4.0f) * 2.0f)));
  const int cy = min(15, max(0, (int)floorf((pi.y + 4.0f) * 2.0f)));
  const int cz = min(15, max(0, (int)floorf((pi.z + 4.0f) * 2.0f)));
  const int x0 = max(cx - 1, 0), x1 = min(cx + 1, 15);
  const int y0 = max(cy - 1, 0), y1 = min(cy + 1, 15);
  const int z0 = max(cz - 1, 0), z1 = min(cz + 1, 15);

  float r[8];
#pragma unroll
  for (int q = 0; q < 8; ++q) r[q] = INF;

  // phase A: top-8 over the <=27-cell block (z-contiguous ranges)
  for (int X = x0; X <= x1; ++X)
    for (int Y = y0; Y <= y1; ++Y) {
      const int cb = (X << 8) | (Y << 4);
      const int s0 = cellptr[cb + z0], s1 = cellptr[cb + z1 + 1];
      for (int c0 = s0; c0 < s1; c0 += 64) {
        const int slot = c0 + lane;
        const int idx = min(slot, s1 - 1);
        const float4 s = pos4s[idx];
        const int nid = perm[idx];
        float d = knn_dist(pi, s);
        float k = (slot < s1 && nid != i) ? d : INF;
        insert8(r, k);
      }
    }
  float tau = merge_tau20(r, lane);

  // exactness margin: distance from query to scanned-region boundary
  float mx = INF, my = INF, mz = INF;
  if (x0 > 0)  mx = pi.x - (x0 * 0.5f - 4.0f);
  if (x1 < 15) mx = fminf(mx, ((x1 + 1) * 0.5f - 4.0f) - pi.x);
  if (y0 > 0)  my = pi.y - (y0 * 0.5f - 4.0f);
  if (y1 < 15) my = fminf(my, ((y1 + 1) * 0.5f - 4.0f) - pi.y);
  if (z0 > 0)  mz = pi.z - (z0 * 0.5f - 4.0f);
  if (z1 < 15) mz = fminf(mz, ((z1 + 1) * 0.5f - 4.0f) - pi.z);
  const float marg = fminf(mx, fminf(my, mz));

  if (tau < marg * marg) {
    // accepted: ball(sqrt(tau)) inside scanned region -> exact neighbor set
    int cnt = 0;
    for (int X = x0; X <= x1; ++X)
      for (int Y = y0; Y <= y1; ++Y) {
        const int cb = (X << 8) | (Y << 4);
        const int s0 = cellptr[cb + z0], s1 = cellptr[cb + z1 + 1];
        for (int c0 = s0; c0 < s1; c0 += 64) {
          const int slot = c0 + lane;
          const int idx = min(slot, s1 - 1);
          const float4 s = pos4s[idx];
          const int nid = perm[idx];
          float d = knn_dist(pi, s);
          bool valid = (slot < s1) && (nid != i);
          emit_hits(i, valid, d, tau, nid, lane, cnt, knn_out);
        }
      }
    return;
  }

  // failed: defer to knn_full (round-6 exact full scan)
  if (lane == 0) {
    int slot = atomicAdd(nfail, 1);
    wl[slot] = i;
  }
}

// ---------------- kNN full scan, block-per-query: 4 waves split the batches ----------------
__global__ __launch_bounds__(256) void knn_full_kernel(
    const float4* __restrict__ pos4, const int* __restrict__ wl,
    const int* __restrict__ nfail, int* __restrict__ knn_out)
{
  __shared__ float wmin[4];
  __shared__ int lcnt, eqcnt;
  __shared__ int eqbuf[64];
  const int tid = threadIdx.x;
  const int lane = tid & 63, wave = tid >> 6;
  const float INF = __builtin_inff();
  const int nf = *nfail;

  for (int w = blockIdx.x; w < nf; w += 2500) {
    const int i = wl[w];
    const float4 pi = pos4[i];

    // phase 1: wave `wave` scans batches b ≡ wave (mod 4); per-lane top-8
    float r[8];
#pragma unroll
    for (int q = 0; q < 8; ++q) r[q] = INF;
    for (int b = wave; b < NBATCH; b += 4) {
      const int cid = b * 64 + lane;
      const float4 s = pos4[cid];
      float d = knn_dist(pi, s);                  // pad rows: +INF
      float k = (cid == i) ? INF : d;
      insert8(r, k);
    }

    // block-level exact tau: 20 extract-min rounds across 4 waves
    float tau = INF;
#pragma unroll
    for (int t = 0; t < KNN_K; ++t) {
      float m = r[0];
      m = fminf(m, __shfl_xor(m, 1));
      m = fminf(m, __shfl_xor(m, 2));
      m = fminf(m, __shfl_xor(m, 4));
      m = fminf(m, __shfl_xor(m, 8));
      m = fminf(m, __shfl_xor(m, 16));
      m = fminf(m, __shfl_xor(m, 32));
      if (lane == 0) wmin[wave] = m;
      __syncthreads();
      float m0 = wmin[0], m1 = wmin[1], m2 = wmin[2], m3 = wmin[3];
      float gm = fminf(fminf(m0, m1), fminf(m2, m3));
      int wsel = (m0 == gm) ? 0 : ((m1 == gm) ? 1 : ((m2 == gm) ? 2 : 3));
      __syncthreads();                             // wmin consumed; safe for next round
      if (wave == wsel) {
        unsigned long long who = __ballot(r[0] == gm);
        int srcl = __ffsll(who) - 1;               // non-empty: wsel's min == gm
        if (lane == srcl) {
#pragma unroll
          for (int z = 0; z < 7; ++z) r[z] = r[z + 1];
          r[7] = INF;
        }
      }
      tau = gm;
    }

    // phase 2: emit. d<tau -> atomic unique slots (set-exact, order-free);
    // d==tau ties -> collect, sort by id, lowest-first fill to 20.
    if (tid == 0) { lcnt = 0; eqcnt = 0; }
    __syncthreads();
    for (int b = wave; b < NBATCH; b += 4) {
      const int cid = b * 64 + lane;
      const float4 s = pos4[cid];
      float d = knn_dist(pi, s);
      bool valid = (cid != i);                     // pad rows: d=INF, never accepted
      if (valid && d < tau) {
        int slot = atomicAdd(&lcnt, 1);
        if (slot < KNN_K) knn_out[i * KNN_K + slot] = cid;
      }
      if (valid && d == tau) {
        int e = atomicAdd(&eqcnt, 1);
        if (e < 64) eqbuf[e] = cid;
      }
    }
    __syncthreads();
    if (tid == 0) {
      int base = lcnt;                             // <= 19 (tau = 20th smallest)
      int ne = min(eqcnt, 64);
      for (int a = 1; a < ne; ++a) {               // tiny insertion sort by id
        int v = eqbuf[a];
        int b2 = a - 1;
        while (b2 >= 0 && eqbuf[b2] > v) { eqbuf[b2 + 1] = eqbuf[b2]; --b2; }
        eqbuf[b2 + 1] = v;
      }
      for (int q = 0; q < ne && base + q < KNN_K; ++q)
        knn_out[i * KNN_K + base + q] = eqbuf[q];
    }
    __syncthreads();                               // lcnt/eqcnt reused next iter
  }
}

// ---------------- reverse-CSR build ----------------
__global__ __launch_bounds__(256) void count_kernel(
    const int* __restrict__ knn, int* __restrict__ counts)
{
  int e = blockIdx.x * 256 + threadIdx.x;
  if (e < NEDGE) atomicAdd(&counts[knn[e]], 1);
}

// node-degree exclusive scan (int4 loads; 250 threads x 40 exact)
__global__ __launch_bounds__(256) void scan_kernel(
    const int* __restrict__ counts, int* __restrict__ rptr)
{
  __shared__ int part[256];
  const int tid = threadIdx.x;
  const int base = tid * 40;                       // 250*40 = 10000 exact
  int s = 0;
  int cv[40];
  if (tid < 250) {
#pragma unroll
    for (int q = 0; q < 10; ++q) {
      int4 v = *(const int4*)&counts[base + q * 4];
      cv[q * 4 + 0] = v.x; cv[q * 4 + 1] = v.y;
      cv[q * 4 + 2] = v.z; cv[q * 4 + 3] = v.w;
      s += v.x + v.y + v.z + v.w;
    }
  }
  part[tid] = s;
  __syncthreads();
  for (int off = 1; off < 256; off <<= 1) {
    int add = (tid >= off) ? part[tid - off] : 0;
    __syncthreads();
    part[tid] += add;
    __syncthreads();
  }
  int run = part[tid] - s;                         // exclusive offset
  if (tid < 250) {
#pragma unroll
    for (int q = 0; q < 40; ++q) { rptr[base + q] = run; run += cv[q]; }
  }
  if (tid == 255) rptr[N_NODES] = run;
}

__global__ __launch_bounds__(256) void fill_kernel(
    const int* __restrict__ knn, const int* __restrict__ rptr,
    int* __restrict__ cursor, int* __restrict__ rsrc)
{
  int e = blockIdx.x * 256 + threadIdx.x;
  if (e < NEDGE) {
    int j = knn[e];
    int i = e / KNN_K;
    int p = atomicAdd(&cursor[j], 1);
    rsrc[rptr[j] + p] = i;
  }
}

// sort each reverse-adjacency list ascending (bitonic-64 per wave)
__global__ __launch_bounds__(256) void sort_kernel(
    const int* __restrict__ rptr, int* __restrict__ rsrc)
{
  const int lane = threadIdx.x & 63, wave = threadIdx.x >> 6;
  const int j = blockIdx.x * 4 + wave;
  const int s0 = rptr[j], s1 = rptr[j + 1], deg = s1 - s0;
  if (deg <= 64) {
    int v = (lane < deg) ? rsrc[s0 + lane] : 0x7FFFFFFF;
#pragma unroll
    for (int k = 2; k <= 64; k <<= 1) {
#pragma unroll
      for (int m = k >> 1; m > 0; m >>= 1) {
        int other = __shfl_xor(v, m);
        bool up = ((lane & k) == 0);
        bool lower = ((lane & m) == 0);
        v = (up == lower) ? min(v, other) : max(v, other);
      }
    }
    if (lane < deg) rsrc[s0 + lane] = v;
  } else if (lane == 0) {
    for (int a = s0 + 1; a < s1; ++a) {
      int v = rsrc[a];
      int b = a - 1;
      while (b >= s0 && rsrc[b] > v) { rsrc[b + 1] = rsrc[b]; --b; }
      rsrc[b + 1] = v;
    }
  }
}

// ---------------- prop: out[j] = scale2 * sum_{i in rev(j)} t[i] - prev[j] ----------------
// XCD-chunked spatial schedule (perm is cell-sorted -> L2-local gathers)
__global__ __launch_bounds__(256) void prop_kernel(
    const unsigned short* __restrict__ tin, const unsigned short* __restrict__ tprev,
    unsigned short* __restrict__ tout, const int* __restrict__ rptr,
    const int* __restrict__ rsrc, const int* __restrict__ perm, float scale2)
{
  const int wave = threadIdx.x >> 6, lane = threadIdx.x & 63;
  const int b = blockIdx.x;                        // grid 2504
  const int xcd = b & 7, qb = b >> 3;
  const int local = qb * 4 + wave;
  if (local >= NPX) return;                        // no barriers below: safe
  const int j = perm[xcd * NPX + local];
  const int s0 = rptr[j], s1 = rptr[j + 1];
  const size_t coff = (size_t)lane * 8;

  float a0[8], a1[8], a2[8], a3[8];
#pragma unroll
  for (int q = 0; q < 8; ++q) { a0[q] = 0.f; a1[q] = 0.f; a2[q] = 0.f; a3[q] = 0.f; }

  for (int base = s0; base < s1; base += 64) {
    const int clen = min(64, s1 - base);
    int myidx = (base + lane < s1) ? rsrc[base + lane] : 0;
    int t = 0;
    for (; t + 4 <= clen; t += 4) {
      int i0 = __shfl(myidx, t);
      int i1 = __shfl(myidx, t + 1);
      int i2 = __shfl(myidx, t + 2);
      int i3 = __shfl(myidx, t + 3);
      uint4 v0 = *(const uint4*)&tin[(size_t)i0 * 512 + coff];
      uint4 v1 = *(const uint4*)&tin[(size_t)i1 * 512 + coff];
      uint4 v2 = *(const uint4*)&tin[(size_t)i2 * 512 + coff];
      uint4 v3 = *(const uint4*)&tin[(size_t)i3 * 512 + coff];
      a0[0] += bf_lo(v0.x); a0[1] += bf_hi(v0.x); a0[2] += bf_lo(v0.y); a0[3] += bf_hi(v0.y);
      a0[4] += bf_lo(v0.z); a0[5] += bf_hi(v0.z); a0[6] += bf_lo(v0.w); a0[7] += bf_hi(v0.w);
      a1[0] += bf_lo(v1.x); a1[1] += bf_hi(v1.x); a1[2] += bf_lo(v1.y); a1[3] += bf_hi(v1.y);
      a1[4] += bf_lo(v1.z); a1[5] += bf_hi(v1.z); a1[6] += bf_lo(v1.w); a1[7] += bf_hi(v1.w);
      a2[0] += bf_lo(v2.x); a2[1] += bf_hi(v2.x); a2[2] += bf_lo(v2.y); a2[3] += bf_hi(v2.y);
      a2[4] += bf_lo(v2.z); a2[5] += bf_hi(v2.z); a2[6] += bf_lo(v2.w); a2[7] += bf_hi(v2.w);
      a3[0] += bf_lo(v3.x); a3[1] += bf_hi(v3.x); a3[2] += bf_lo(v3.y); a3[3] += bf_hi(v3.y);
      a3[4] += bf_lo(v3.z); a3[5] += bf_hi(v3.z); a3[6] += bf_lo(v3.w); a3[7] += bf_hi(v3.w);
    }
    for (; t < clen; ++t) {
      int i0 = __shfl(myidx, t);
      uint4 v0 = *(const uint4*)&tin[(size_t)i0 * 512 + coff];
      a0[0] += bf_lo(v0.x); a0[1] += bf_hi(v0.x); a0[2] += bf_lo(v0.y); a0[3] += bf_hi(v0.y);
      a0[4] += bf_lo(v0.z); a0[5] += bf_hi(v0.z); a0[6] += bf_lo(v0.w); a0[7] += bf_hi(v0.w);
    }
  }

  float pv[8] = {0.f, 0.f, 0.f, 0.f, 0.f, 0.f, 0.f, 0.f};
  if (tprev != nullptr) {
    uint4 p = *(const uint4*)&tprev[(size_t)j * 512 + coff];
    pv[0] = bf_lo(p.x); pv[1] = bf_hi(p.x);
    pv[2] = bf_lo(p.y); pv[3] = bf_hi(p.y);
    pv[4] = bf_lo(p.z); pv[5] = bf_hi(p.z);
    pv[6] = bf_lo(p.w); pv[7] = bf_hi(p.w);
  }
  unsigned short o16[8];
#pragma unroll
  for (int q = 0; q < 8; ++q) {
    float acc = (a0[q] + a1[q]) + (a2[q] + a3[q]);   // fixed tree, deterministic
    o16[q] = f2bf(scale2 * acc - pv[q]);
  }
  uint4 o;
  o.x = (unsigned int)o16[0] | ((unsigned int)o16[1] << 16);
  o.y = (unsigned int)o16[2] | ((unsigned int)o16[3] << 16);
  o.z = (unsigned int)o16[4] | ((unsigned int)o16[5] << 16);
  o.w = (unsigned int)o16[6] | ((unsigned int)o16[7] << 16);
  *(uint4*)&tout[(size_t)j * 512 + coff] = o;
}

// ---------------- GEMM: C[o][n] = sum_kc A[n][kc] * B[kc][o] + bias[o] ----------------
// 64n x 128o tile, 628 blocks (~2.5/CU TLP). Double-buffered LDS (48KB) +
// counted-vmcnt(6) pipeline + T2 XOR swizzle + bijective XCD chunking.
// Wave w computes n[0..64) x o[w*32..w*32+32): acc[4][2].
__global__ __launch_bounds__(256) void gemm_kernel(
    const unsigned short* __restrict__ A,
    const unsigned short* __restrict__ Bt,
    const float* __restrict__ bias,
    float* __restrict__ C)
{
  __shared__ __align__(16) char smem[49152];          // 2 x (As 8KB + Bs 16KB); epi 34KB
  float* eps = (float*)smem;                          // epilogue [128 o][68 n] f32

  const int tid = threadIdx.x;
  const int wave = tid >> 6, lane = tid & 63;
  const int l15 = lane & 15, hi = lane >> 4;

  // bijective XCD-chunked mapping of 628 (n,o) pairs, n-major
  const int bid = blockIdx.x;                         // 0..631
  const int xcd = bid & 7, local = bid >> 3;
  const int qd = GM_PAIRS >> 3, rem = GM_PAIRS & 7;   // 78, 4
  const int cnt = (xcd < rem) ? qd + 1 : qd;
  if (local >= cnt) return;                           // whole block exits: safe
  const int start = (xcd < rem) ? xcd * (qd + 1) : rem * (qd + 1) + (xcd - rem) * qd;
  const int pair = start + local;
  const int n0 = (pair >> 2) * 64;                    // 0..9984 (overread in pad)
  const int o0 = (pair & 3) * 128;

  f32x4 acc[4][2];
#pragma unroll
  for (int a = 0; a < 4; ++a)
#pragma unroll
    for (int b = 0; b < 2; ++b) acc[a][b] = (f32x4){0.f, 0.f, 0.f, 0.f};

  // stage K-tile kt into buffer sel (6 gll16/thread: A 2, B 4).
  // LDS dest linear; global 16B-unit column pre-swizzled u_g = u ^ (r&7).
  auto stage = [&](int kt, int sel) {
    const int k0 = kt * 64;
    const int ko = k0 >> 9;
    const int c0 = k0 & 511;
    const unsigned short* Ab = A + (size_t)ko * ((size_t)N_NODES * 512);
    unsigned short* As = (unsigned short*)(smem + sel * 24576);
    unsigned short* Bs = As + 64 * 64;                // A 8KB, then B 16KB
#pragma unroll
    for (int q = 0; q < 2; ++q) {                     // A: 512 units
      int idx = (wave * 2 + q) * 64 + lane;
      int r = idx >> 3, u = idx & 7;
      int ug = u ^ (r & 7);
      gll16(Ab + (size_t)(n0 + r) * 512 + c0 + ug * 8, As + (size_t)(wave * 2 + q) * 512);
    }
#pragma unroll
    for (int q = 0; q < 4; ++q) {                     // B: 1024 units
      int idx = (wave * 4 + q) * 64 + lane;
      int r = idx >> 3, u = idx & 7;
      int ug = u ^ (r & 7);
      gll16(Bt + (size_t)(o0 + r) * 2560 + k0 + ug * 8, Bs + (size_t)(wave * 4 + q) * 512);
    }
  };

  stage(0, 0);
  asm volatile("s_waitcnt vmcnt(0)" ::: "memory");     // tile 0 resident
  __builtin_amdgcn_s_barrier();

  for (int kt = 0; kt < 40; ++kt) {
    const int cur = kt & 1;
    if (kt + 1 < 40) {
      stage(kt + 1, cur ^ 1);                          // 6 loads join flight
      asm volatile("s_waitcnt vmcnt(6)" ::: "memory"); // my tile-kt 6 complete
    } else {
      asm volatile("s_waitcnt vmcnt(0)" ::: "memory");
    }
    __builtin_amdgcn_s_barrier();                      // all waves: tile kt in LDS
    __builtin_amdgcn_sched_barrier(0);                 // pin ds_reads below
    unsigned short* As = (unsigned short*)(smem + cur * 24576);
    unsigned short* Bs = As + 64 * 64;
#pragma unroll
    for (int kk = 0; kk < 2; ++kk) {
      bf16x8 af[4], bfr[2];
#pragma unroll
      for (int mi = 0; mi < 4; ++mi) {
        int row = mi * 16 + l15;                       // 0..63
        int up = (kk * 4 + hi) ^ (row & 7);            // read-side XOR
        af[mi] = *(const bf16x8*)(As + row * 64 + up * 8);
      }
#pragma unroll
      for (int ni = 0; ni < 2; ++ni) {
        int row = wave * 32 + ni * 16 + l15;           // 0..127
        int up = (kk * 4 + hi) ^ (row & 7);
        bfr[ni] = *(const bf16x8*)(Bs + row * 64 + up * 8);
      }
#pragma unroll
      for (int mi = 0; mi < 4; ++mi)
#pragma unroll
        for (int ni = 0; ni < 2; ++ni)
          acc[mi][ni] = __builtin_amdgcn_mfma_f32_16x16x32_bf16(af[mi], bfr[ni], acc[mi][ni], 0, 0, 0);
    }
    __builtin_amdgcn_s_barrier();                      // reads done before overwrite
  }

  // epilogue: waves own disjoint o-ranges -> single pass
  __syncthreads();                                     // protect smem from K-loop reuse
#pragma unroll
  for (int mi = 0; mi < 4; ++mi)
#pragma unroll
    for (int ni = 0; ni < 2; ++ni) {
      int o_l = wave * 32 + ni * 16 + l15;             // 0..127
      int nb = mi * 16 + hi * 4;                       // 0..60
      *(f32x4*)&eps[o_l * 68 + nb] = acc[mi][ni];
    }
  __syncthreads();
#pragma unroll
  for (int q = 0; q < 8; ++q) {
    int unit = q * 256 + tid;                          // 2048 float4 units
    int o_l = unit >> 4, nu = unit & 15;
    int n = n0 + nu * 4;
    if (n < N_NODES) {
      int o = o0 + o_l;
      f32x4 v = *(const f32x4*)&eps[o_l * 68 + nu * 4];
      float bo = bias[o];
      v = v + bo;
      *(f32x4*)&C[(size_t)o * N_NODES + n] = v;
    }
  }
}

extern "C" void kernel_launch(void* const* d_in, const int* in_sizes, int n_in,
                              void* d_out, int out_size, void* d_ws, size_t ws_size,
                              hipStream_t stream)
{
  const float* x        = (const float*)d_in[0];   // [512][10000]
  const float* position = (const float*)d_in[1];   // [10000][3]
  const float* theta    = (const float*)d_in[2];   // [5][512][512]
  const float* bias     = (const float*)d_in[3];   // [512]

  char* ws = (char*)d_ws;
  size_t off = 0;
  auto alloc = [&](size_t bytes) -> void* {
    void* p = ws + off;
    off = (off + bytes + 255) & ~(size_t)255;
    return p;
  };
  unsigned short* TxAll   = (unsigned short*)alloc(5ull * N_NODES * 512 * 2 + 131072); // +128-row pad
  unsigned short* thetabT = (unsigned short*)alloc(512ull * 2560 * 2);
  float4* pos4  = (float4*)alloc((size_t)POS4_PAD * 16);
  float4* pos4s = (float4*)alloc((size_t)N_NODES * 16);
  int* knn    = (int*)alloc((size_t)NEDGE * 4);
  int* rptr   = (int*)alloc((size_t)(N_NODES + 1) * 4);
  int* counts = (int*)alloc((size_t)N_NODES * 4);
  int* cursor = (int*)alloc((size_t)N_NODES * 4);
  int* rsrc   = (int*)alloc((size_t)NEDGE * 4);
  int* cellcnt = (int*)alloc((size_t)NCELL * 4);   // contiguous with cellcur:
  int* cellcur = (int*)alloc((size_t)NCELL * 4);   // one memset covers both
  int* cellptr = (int*)alloc((size_t)(NCELL + 1) * 4);
  int* cellid  = (int*)alloc((size_t)N_NODES * 4);
  int* perm    = (int*)alloc((size_t)N_NODES * 4);
  int* wl      = (int*)alloc((size_t)N_NODES * 4);
  int* nfail   = (int*)alloc(256);
  if (ws_size < off) return;   // insufficient scratch

  // theta [5][512][512] -> thetabT [o=512][kc=2560]
  transpose_f32_bf16<<<dim3(8, 8, 5), 256, 0, stream>>>(
      theta, thetabT, 512, 512, 2560, (size_t)512 * 512, 512);
  // x [512][10000] -> Tx0 [10000][512]
  transpose_f32_bf16<<<dim3(157, 8, 1), 256, 0, stream>>>(
      x, TxAll, 512, N_NODES, 512, 0, 0);

  hipMemsetAsync(cellcnt, 0, (size_t)((char*)cellptr - (char*)cellcnt), stream);
  pos4_kernel<<<40, 256, 0, stream>>>(position, pos4, counts, cursor, cellid, cellcnt, nfail);
  cellscan_kernel<<<1, 256, 0, stream>>>(cellcnt, cellptr);
  perm_kernel<<<40, 256, 0, stream>>>(cellid, cellptr, cellcur, perm, pos4, pos4s);

  knn_try_kernel<<<2500, 256, 0, stream>>>(pos4, pos4s, perm, cellptr, knn, wl, nfail);
  knn_full_kernel<<<2500, 256, 0, stream>>>(pos4, wl, nfail, knn);

  count_kernel<<<(NEDGE + 255) / 256, 256, 0, stream>>>(knn, counts);
  scan_kernel<<<1, 256, 0, stream>>>(counts, rptr);
  fill_kernel<<<(NEDGE + 255) / 256, 256, 0, stream>>>(knn, rptr, cursor, rsrc);
  sort_kernel<<<2500, 256, 0, stream>>>(rptr, rsrc);

  unsigned short* Tx0 = TxAll;
  unsigned short* Tx1 = TxAll + 1ull * N_NODES * 512;
  unsigned short* Tx2 = TxAll + 2ull * N_NODES * 512;
  unsigned short* Tx3 = TxAll + 3ull * N_NODES * 512;
  unsigned short* Tx4 = TxAll + 4ull * N_NODES * 512;

  // Tx1 = prop(Tx0) = -0.05*sum ; Tx_k = 2*prop(Tx_{k-1}) - Tx_{k-2} = -0.10*sum - prev
  prop_kernel<<<2504, 256, 0, stream>>>(Tx0, nullptr, Tx1, rptr, rsrc, perm, -0.05f);
  prop_kernel<<<2504, 256, 0, stream>>>(Tx1, Tx0,     Tx2, rptr, rsrc, perm, -0.10f);
  prop_kernel<<<2504, 256, 0, stream>>>(Tx2, Tx1,     Tx3, rptr, rsrc, perm, -0.10f);
  prop_kernel<<<2504, 256, 0, stream>>>(Tx3, Tx2,     Tx4, rptr, rsrc, perm, -0.10f);

  gemm_kernel<<<632, 256, 0, stream>>>(TxAll, thetabT, bias, (float*)d_out);
}